// Round 1
// baseline (13433.640 us; speedup 1.0000x reference)
//
#include <hip/hip_runtime.h>
#include <math.h>

// ---- problem dims ----
#define BN_ 650
#define T_ 48
#define C_ 128
#define V_ 3
#define T2_ 12
#define L_ 4
#define H_ 8
#define D_ 64
#define HD_ 512
#define DIN_ 387
#define NB_ 6
#define NROWS_ 7800          // BN_*T2_
#define LOG2PI_ 1.8378770664093453f

// ---- workspace layout (float offsets) ----
#define WS_AV 0
#define WS_U  (WS_AV + NROWS_*HD_)       // att_value [7800][512]
#define WS_LD (WS_U + NROWS_*V_)         // u  [7800][3]
#define WS_SRAW (WS_LD + NROWS_*V_)      // ld [7800][3]
#define WS_SAB  (WS_SRAW + NB_*36*2)     // raw sums [6][36][2]
#define WS_LDA  (WS_SAB + NB_*36*2)      // (a,c)    [6][36][2]
// WS_LDA: [6][36] log-det add

// ============================================================
// Transformer: one workgroup per bn row; shift + 4 layers fused.
// ============================================================
__device__ __forceinline__ void layernorm_rows(float (*av)[HD_], float (*res)[HD_],
    const float* __restrict__ s, const float* __restrict__ b, int tid)
{
  const int wv_ = tid >> 6, lane = tid & 63;
  for (int v = wv_; v < T2_; v += 8) {
    float x[8]; float sm = 0.f, s2 = 0.f;
    #pragma unroll
    for (int j = 0; j < 8; j++) {
      float t = av[v][lane + 64*j] + res[v][lane + 64*j];
      x[j] = t; sm += t; s2 += t * t;
    }
    #pragma unroll
    for (int o = 32; o; o >>= 1) { sm += __shfl_xor(sm, o); s2 += __shfl_xor(s2, o); }
    float mean = sm * (1.f / HD_);
    float var  = s2 * (1.f / HD_) - mean * mean;
    float r = rsqrtf(var + 1e-5f);
    #pragma unroll
    for (int j = 0; j < 8; j++) {
      int c = lane + 64*j;
      av[v][c] = (x[j] - mean) * r * s[c] + b[c];
    }
  }
}

// acc[m] = in[m][:] @ w[:, tid] + bias (K = 512)
__device__ __forceinline__ void gemm512_col(const float (*in)[HD_], const float* __restrict__ w,
    float bias, int tid, float* acc)
{
  #pragma unroll
  for (int m = 0; m < T2_; m++) acc[m] = bias;
  const float* wp = w + tid;
  for (int k4 = 0; k4 < HD_/4; k4++) {
    float w0 = wp[(k4*4+0)*HD_], w1 = wp[(k4*4+1)*HD_];
    float w2 = wp[(k4*4+2)*HD_], w3 = wp[(k4*4+3)*HD_];
    #pragma unroll
    for (int m = 0; m < T2_; m++) {
      const float4 x = *reinterpret_cast<const float4*>(&in[m][k4*4]);
      acc[m] = fmaf(x.x, w0, fmaf(x.y, w1, fmaf(x.z, w2, fmaf(x.w, w3, acc[m]))));
    }
  }
}

__global__ __launch_bounds__(512)
void transformer_kernel(const float* __restrict__ enc, const float* __restrict__ tvg,
    const float* __restrict__ Wsh, const float* __restrict__ bsh,
    const float* __restrict__ Wk,  const float* __restrict__ bk,
    const float* __restrict__ Wv,  const float* __restrict__ bvv,
    const float* __restrict__ ln1s, const float* __restrict__ ln1b,
    const float* __restrict__ fw1, const float* __restrict__ fb1,
    const float* __restrict__ fw2, const float* __restrict__ fb2,
    const float* __restrict__ ln2s, const float* __restrict__ ln2b,
    float* __restrict__ avout)
{
  const int b = blockIdx.x;
  const int tid = threadIdx.x;
  const float* encb = enc + (size_t)b * V_ * T_ * C_;
  const float* tvb  = tvg + (size_t)b * V_ * T_;

  __shared__ float av [T2_][HD_];
  __shared__ float kh [T_][D_+1];
  __shared__ float vh [T_][D_+1];
  __shared__ float sc [T2_][T_];
  __shared__ float tmp[T2_][HD_];   // attn out / FF2 out
  __shared__ float ffh[T2_][HD_];   // FF hidden

  // ---- initial shift: av[m][tid] = att_in[m] @ W_shift[:,tid] + b ----
  {
    float acc[T2_];
    float bb = bsh[tid];
    #pragma unroll
    for (int m = 0; m < T2_; m++) acc[m] = bb;
    for (int vv = 0; vv < V_; vv++) {
      const float* ep = encb + vv * T_ * C_ + (T_ - T2_) * C_;  // rows 36..47
      for (int c4 = 0; c4 < C_/4; c4++) {
        const float* wp = Wsh + (vv * C_ + c4*4) * HD_ + tid;
        float w0 = wp[0], w1 = wp[HD_], w2 = wp[2*HD_], w3 = wp[3*HD_];
        #pragma unroll
        for (int m = 0; m < T2_; m++) {
          const float4 e = *reinterpret_cast<const float4*>(ep + m * C_ + c4*4);
          acc[m] = fmaf(e.x, w0, fmaf(e.y, w1, fmaf(e.z, w2, fmaf(e.w, w3, acc[m]))));
        }
      }
    }
    #pragma unroll
    for (int m = 0; m < T2_; m++) av[m][tid] = acc[m];
  }
  __syncthreads();

  for (int l = 0; l < L_; l++) {
    // ---------- attention ----------
    const int d  = tid & 63;
    const int m0 = __builtin_amdgcn_readfirstlane(tid >> 6);   // wave-uniform 0..7
    for (int h = 0; h < H_; h++) {
      float ka[6], va[6];
      float kb = bk [(l*H_ + h)*D_ + d];
      float vb = bvv[(l*H_ + h)*D_ + d];
      #pragma unroll
      for (int j = 0; j < 6; j++) { ka[j] = kb; va[j] = vb; }
      const float* wkp = Wk + (size_t)(l*H_ + h) * DIN_ * D_ + d;
      const float* wvp = Wv + (size_t)(l*H_ + h) * DIN_ * D_ + d;
      for (int vv = 0; vv < V_; vv++) {
        const float* ep = encb + vv * T_ * C_;
        for (int c4 = 0; c4 < C_/4; c4++) {
          const int e0 = (vv*129 + c4*4) * D_;
          float wk0 = wkp[e0], wk1 = wkp[e0+D_], wk2 = wkp[e0+2*D_], wk3 = wkp[e0+3*D_];
          float wv0 = wvp[e0], wv1 = wvp[e0+D_], wv2 = wvp[e0+2*D_], wv3 = wvp[e0+3*D_];
          #pragma unroll
          for (int j = 0; j < 6; j++) {
            const float4 e = *reinterpret_cast<const float4*>(ep + (m0 + 8*j) * C_ + c4*4);
            ka[j] = fmaf(e.x, wk0, fmaf(e.y, wk1, fmaf(e.z, wk2, fmaf(e.w, wk3, ka[j]))));
            va[j] = fmaf(e.x, wv0, fmaf(e.y, wv1, fmaf(e.z, wv2, fmaf(e.w, wv3, va[j]))));
          }
        }
        float wkt = wkp[(vv*129 + 128) * D_];
        float wvt = wvp[(vv*129 + 128) * D_];
        #pragma unroll
        for (int j = 0; j < 6; j++) {
          float tvv = tvb[vv * T_ + m0 + 8*j];
          ka[j] = fmaf(tvv, wkt, ka[j]);
          va[j] = fmaf(tvv, wvt, va[j]);
        }
      }
      #pragma unroll
      for (int j = 0; j < 6; j++) { kh[m0 + 8*j][d] = ka[j]; vh[m0 + 8*j][d] = va[j]; }
      __syncthreads();

      // scores [12][48]
      for (int idx = tid; idx < T2_ * T_; idx += 512) {
        int v = idx / T_, w = idx - v * T_;
        float s;
        if (w < 36 + v) {
          s = 0.f;
          const float* avp = &av[v][h * D_];
          #pragma unroll 8
          for (int i = 0; i < D_; i++) s = fmaf(avp[i], kh[w][i], s);
          s *= 0.125f;
        } else s = -1e30f;
        sc[v][w] = s;
      }
      __syncthreads();

      // softmax per query row (rows are tiny: 48 keys)
      if (tid < T2_) {
        const int v = tid, nv = 36 + v;
        float mx = -1e30f;
        for (int w = 0; w < nv; w++) mx = fmaxf(mx, sc[v][w]);
        float sum = 0.f;
        for (int w = 0; w < nv; w++) { float p = expf(sc[v][w] - mx); sc[v][w] = p; sum += p; }
        float inv = 1.f / sum;
        for (int w = 0; w < nv; w++) sc[v][w] *= inv;
        for (int w = nv; w < T_; w++) sc[v][w] = 0.f;
      }
      __syncthreads();

      // att out → tmp[v][h*64+d]
      for (int idx = tid; idx < T2_ * D_; idx += 512) {
        int v = idx >> 6, dd = idx & 63;
        float a = 0.f;
        #pragma unroll 8
        for (int w = 0; w < T_; w++) a = fmaf(sc[v][w], vh[w][dd], a);
        tmp[v][h * D_ + dd] = a;
      }
      __syncthreads();
    }

    // LN1: av = LN(av + tmp)
    layernorm_rows(av, tmp, ln1s + l*HD_, ln1b + l*HD_, tid);
    __syncthreads();

    // FF1: ffh = relu(av @ w1 + b1)
    {
      float a1[T2_];
      gemm512_col(av, fw1 + (size_t)l*HD_*HD_, fb1[l*HD_ + tid], tid, a1);
      #pragma unroll
      for (int m = 0; m < T2_; m++) ffh[m][tid] = fmaxf(a1[m], 0.f);
    }
    __syncthreads();
    // FF2: tmp = ffh @ w2 + b2
    {
      float a2[T2_];
      gemm512_col(ffh, fw2 + (size_t)l*HD_*HD_, fb2[l*HD_ + tid], tid, a2);
      #pragma unroll
      for (int m = 0; m < T2_; m++) tmp[m][tid] = a2[m];
    }
    __syncthreads();
    // LN2: av = LN(av + tmp)
    layernorm_rows(av, tmp, ln2s + l*HD_, ln2b + l*HD_, tid);
    __syncthreads();
  }

  #pragma unroll
  for (int m = 0; m < T2_; m++) avout[((size_t)b * T2_ + m) * HD_ + tid] = av[m][tid];
}

// ============================================================
// RealNVP block: s-net + t-net MLPs for a 32-row tile, coupling
// update, and raw batch-stat accumulation.
// ============================================================
__global__ __launch_bounds__(512)
void nvp_kernel(const float* __restrict__ avg, const float* __restrict__ tvg,
    float* __restrict__ u, float* __restrict__ ld, float* __restrict__ sraw,
    const float* __restrict__ sab,
    const float* __restrict__ swin, const float* __restrict__ sbin,
    const float* __restrict__ swhid, const float* __restrict__ sbhid,
    const float* __restrict__ swout, const float* __restrict__ sbout,
    const float* __restrict__ twin, const float* __restrict__ tbin,
    const float* __restrict__ twhid, const float* __restrict__ tbhid,
    const float* __restrict__ twout, const float* __restrict__ tbout,
    int blk)
{
  const int tid  = threadIdx.x;
  const int base = blockIdx.x * 32;

  __shared__ float inp [32][516];   // [y(512) | mu(3) | pad]
  __shared__ float h   [32][516];
  __shared__ float uin [32][4];
  __shared__ float sout[32][4];

  // ---- load inp ----
  for (int m = 0; m < 32; m++) {
    int r = base + m;
    inp[m][tid] = (r < NROWS_) ? avg[(size_t)r * HD_ + tid] : 0.f;
  }
  if (tid < 32) {
    const int m = tid, r = base + m;
    float uv[3] = {0.f, 0.f, 0.f};
    if (r < NROWS_) {
      int bn = r / T2_, t2 = r - bn * T2_;
      if (blk == 0) {
        #pragma unroll
        for (int v = 0; v < 3; v++) uv[v] = tvg[((size_t)bn * V_ + v) * T_ + (T_ - T2_) + t2];
      } else {
        #pragma unroll
        for (int v = 0; v < 3; v++) {
          float a = sab[((blk-1)*36 + t2*3 + v)*2 + 0];
          float c = sab[((blk-1)*36 + t2*3 + v)*2 + 1];
          uv[v] = fmaf(a, u[(size_t)r*3 + v], c);
        }
      }
    }
    #pragma unroll
    for (int v = 0; v < 3; v++) {
      uin[m][v] = uv[v];
      int msk = (v + blk) & 1;
      inp[m][512 + v] = msk ? uv[v] : 0.f;
    }
    inp[m][515] = 0.f;
  }
  __syncthreads();

  float t_out_val = 0.f;
  for (int net = 0; net < 2; net++) {
    const float* wi = (net ? twin  : swin ) + (size_t)blk * 515 * HD_;
    const float* bi = (net ? tbin  : sbin ) + blk * HD_;
    const float* wh = (net ? twhid : swhid) + (size_t)blk * 4 * HD_ * HD_;
    const float* bh = (net ? tbhid : sbhid) + blk * 4 * HD_;
    const float* wo = (net ? twout : swout) + (size_t)blk * HD_ * 3;
    const float* bo = (net ? tbout : sbout) + blk * 3;

    // ---- layer 0: inp(515) -> h ----
    {
      float acc[32];
      #pragma unroll
      for (int m = 0; m < 32; m++) acc[m] = 0.f;
      const float* wp = wi + tid;
      for (int k4 = 0; k4 < 128; k4++) {
        float w0 = wp[(k4*4+0)*HD_], w1 = wp[(k4*4+1)*HD_];
        float w2 = wp[(k4*4+2)*HD_], w3 = wp[(k4*4+3)*HD_];
        #pragma unroll
        for (int m = 0; m < 32; m++) {
          const float4 x = *reinterpret_cast<const float4*>(&inp[m][k4*4]);
          acc[m] = fmaf(x.x, w0, fmaf(x.y, w1, fmaf(x.z, w2, fmaf(x.w, w3, acc[m]))));
        }
      }
      #pragma unroll
      for (int k = 512; k < 515; k++) {
        float w = wp[k * HD_];
        #pragma unroll
        for (int m = 0; m < 32; m++) acc[m] = fmaf(inp[m][k], w, acc[m]);
      }
      float bb = bi[tid];
      #pragma unroll
      for (int m = 0; m < 32; m++) {
        float hv = acc[m] + bb;
        h[m][tid] = net ? fmaxf(hv, 0.f) : tanhf(hv);
      }
    }
    __syncthreads();

    // ---- 4 hidden layers ----
    for (int i = 0; i < 4; i++) {
      float acc[32];
      #pragma unroll
      for (int m = 0; m < 32; m++) acc[m] = 0.f;
      const float* wp = wh + (size_t)i * HD_ * HD_ + tid;
      for (int k4 = 0; k4 < 128; k4++) {
        float w0 = wp[(k4*4+0)*HD_], w1 = wp[(k4*4+1)*HD_];
        float w2 = wp[(k4*4+2)*HD_], w3 = wp[(k4*4+3)*HD_];
        #pragma unroll
        for (int m = 0; m < 32; m++) {
          const float4 x = *reinterpret_cast<const float4*>(&h[m][k4*4]);
          acc[m] = fmaf(x.x, w0, fmaf(x.y, w1, fmaf(x.z, w2, fmaf(x.w, w3, acc[m]))));
        }
      }
      float bb = bh[i * HD_ + tid];
      __syncthreads();   // all reads of h done before overwrite
      #pragma unroll
      for (int m = 0; m < 32; m++) {
        float hv = acc[m] + bb;
        h[m][tid] = net ? fmaxf(hv, 0.f) : tanhf(hv);
      }
      __syncthreads();
    }

    // ---- out layer (96 outputs) ----
    if (tid < 96) {
      int m = tid / 3, j = tid - 3 * (tid / 3);
      float acc = 0.f;
      const float* wp = wo + j;
      #pragma unroll 8
      for (int k = 0; k < HD_; k++) acc = fmaf(h[m][k], wp[k*3], acc);
      acc += bo[j];
      if (net == 0) sout[m][j] = acc; else t_out_val = acc;
    }
    __syncthreads();
  }

  // ---- coupling update + stats ----
  if (tid < 96) {
    int m = tid / 3, j = tid - 3 * (tid / 3);
    int r = base + m;
    if (r < NROWS_) {
      int msk = (j + blk) & 1;
      float s  = sout[m][j];
      float uo = uin[m][j];
      float unew = msk ? uo : (uo - t_out_val) * expf(-s);
      u[(size_t)r*3 + j] = unew;
      float prev = (blk == 0) ? 0.f : ld[(size_t)r*3 + j];
      ld[(size_t)r*3 + j] = prev - (msk ? 0.f : s);
      int t2 = r % T2_;
      atomicAdd(&sraw[(blk*36 + t2*3 + j)*2 + 0], unew);
      atomicAdd(&sraw[(blk*36 + t2*3 + j)*2 + 1], unew * unew);
    }
  }
}

__global__ void zero_stats_kernel(float* __restrict__ sraw)
{
  int i = threadIdx.x + blockIdx.x * blockDim.x;
  if (i < NB_*36*2) sraw[i] = 0.f;
}

__global__ void bn_finalize_kernel(const float* __restrict__ sraw, float* __restrict__ sab,
    float* __restrict__ ldadd, const float* __restrict__ lg, const float* __restrict__ bt, int blk)
{
  int idx = threadIdx.x;
  if (idx < 36) {
    int v = idx % 3;
    float sum = sraw[(blk*36 + idx)*2 + 0];
    float s2  = sraw[(blk*36 + idx)*2 + 1];
    float bm  = sum * (1.f / 650.f);
    float bvr = s2 * (1.f / 650.f) - bm * bm;
    float g = lg[blk*3 + v];
    float a = expf(g) * rsqrtf(bvr + 1e-5f);
    float c = bt[blk*3 + v] - a * bm;
    sab[(blk*36 + idx)*2 + 0] = a;
    sab[(blk*36 + idx)*2 + 1] = c;
    ldadd[blk*36 + idx] = g - 0.5f * logf(bvr + 1e-5f);
  }
}

__global__ void loss_kernel(const float* __restrict__ u, const float* __restrict__ ld,
    const float* __restrict__ sab, const float* __restrict__ ldadd, float* __restrict__ out)
{
  int bn = blockIdx.x * blockDim.x + threadIdx.x;
  if (bn >= BN_) return;
  float acc = 0.f;
  for (int t2 = 0; t2 < T2_; t2++) {
    #pragma unroll
    for (int v = 0; v < 3; v++) {
      int idx = t2*3 + v;
      float a = sab[(5*36 + idx)*2 + 0];
      float c = sab[(5*36 + idx)*2 + 1];
      float ur = u[((size_t)bn * T2_ + t2)*3 + v];
      float ub = fmaf(a, ur, c);
      acc += 0.5f * ub * ub + 0.5f * LOG2PI_ - ld[((size_t)bn * T2_ + t2)*3 + v];
    }
  }
  float lsum = 0.f;
  for (int i = 0; i < NB_*36; i++) lsum += ldadd[i];
  out[bn] = acc - lsum;
}

// ============================================================
extern "C" void kernel_launch(void* const* d_in, const int* in_sizes, int n_in,
                              void* d_out, int out_size, void* d_ws, size_t ws_size,
                              hipStream_t stream)
{
  const float* enc   = (const float*)d_in[0];
  const float* tv    = (const float*)d_in[1];
  const float* Wsh   = (const float*)d_in[2];
  const float* bsh   = (const float*)d_in[3];
  const float* Wk    = (const float*)d_in[4];
  const float* bk    = (const float*)d_in[5];
  const float* Wv    = (const float*)d_in[6];
  const float* bv    = (const float*)d_in[7];
  const float* ln1s  = (const float*)d_in[8];
  const float* ln1b  = (const float*)d_in[9];
  const float* fw1   = (const float*)d_in[10];
  const float* fb1   = (const float*)d_in[11];
  const float* fw2   = (const float*)d_in[12];
  const float* fb2   = (const float*)d_in[13];
  const float* ln2s  = (const float*)d_in[14];
  const float* ln2b  = (const float*)d_in[15];
  const float* swin  = (const float*)d_in[16];
  const float* sbin  = (const float*)d_in[17];
  const float* swhid = (const float*)d_in[18];
  const float* sbhid = (const float*)d_in[19];
  const float* swout = (const float*)d_in[20];
  const float* sbout = (const float*)d_in[21];
  const float* twin  = (const float*)d_in[22];
  const float* tbin  = (const float*)d_in[23];
  const float* twhid = (const float*)d_in[24];
  const float* tbhid = (const float*)d_in[25];
  const float* twout = (const float*)d_in[26];
  const float* tbout = (const float*)d_in[27];
  const float* bnlg  = (const float*)d_in[28];
  const float* bnbt  = (const float*)d_in[29];

  float* ws   = (float*)d_ws;
  float* av   = ws + WS_AV;
  float* u    = ws + WS_U;
  float* ld   = ws + WS_LD;
  float* sraw = ws + WS_SRAW;
  float* sab  = ws + WS_SAB;
  float* lda  = ws + WS_LDA;
  float* out  = (float*)d_out;

  transformer_kernel<<<BN_, 512, 0, stream>>>(enc, tv, Wsh, bsh, Wk, bk, Wv, bv,
      ln1s, ln1b, fw1, fb1, fw2, fb2, ln2s, ln2b, av);
  zero_stats_kernel<<<1, 512, 0, stream>>>(sraw);
  for (int blk = 0; blk < NB_; blk++) {
    nvp_kernel<<<(NROWS_ + 31) / 32, 512, 0, stream>>>(av, tv, u, ld, sraw, sab,
        swin, sbin, swhid, sbhid, swout, sbout,
        twin, tbin, twhid, tbhid, twout, tbout, blk);
    bn_finalize_kernel<<<1, 64, 0, stream>>>(sraw, sab, lda, bnlg, bnbt, blk);
  }
  loss_kernel<<<(BN_ + 255) / 256, 256, 0, stream>>>(u, ld, sab, lda, out);
}

// Round 2
// 3444.022 us; speedup vs baseline: 3.9006x; 3.9006x over previous
//
#include <hip/hip_runtime.h>
#include <math.h>

// ---- problem dims ----
#define BN_ 650
#define T_ 48
#define V_ 3
#define T2_ 12
#define NROWS_ 7800            // BN_*T2_
#define MKV_ 31200             // BN_*T_
#define LOG2PI_ 1.8378770664093453f

typedef short s8v __attribute__((ext_vector_type(8)));
typedef float f4v __attribute__((ext_vector_type(4)));

__device__ __forceinline__ float b2f(unsigned short h) {
  return __uint_as_float(((unsigned)h) << 16);
}
__device__ __forceinline__ unsigned short f2b(float f) {
  unsigned u = __float_as_uint(f);
  return (unsigned short)((u + 0x7fffu + ((u >> 16) & 1u)) >> 16);
}

// ============================================================
// Canonical bf16 MFMA GEMM: C[M,N] = act(A[M,Kp] @ BT[N,Kp]^T + bias) (+res)
// BT is pre-transposed [N][Kp] bf16. Tiles: BM x 128, 256 thr, 4 waves.
// ============================================================
struct GZ {
  const unsigned short* A;
  const unsigned short* B;
  const float* bias;
  unsigned short* C;
  const unsigned short* res;
  int act;   // 0 none, 1 relu, 2 tanh
};

template<int BM>
__global__ __launch_bounds__(256)
void gemm_bf16(GZ g0, GZ g1, int M, int Kp,
               unsigned short* __restrict__ kvb,
               const float* __restrict__ kb0, const float* __restrict__ kb1)
{
  constexpr int MF = BM / 32;      // m-frags per wave
  constexpr int AU = BM / 32;      // A b128 units per thread
  __shared__ __align__(16) unsigned short As[2][BM * 72];
  __shared__ __align__(16) unsigned short Bs[2][128 * 72];
  GZ g = (blockIdx.z == 0) ? g0 : g1;
  const int tid = threadIdx.x;
  const int lane = tid & 63;
  const int wid = tid >> 6;
  const int wm = wid >> 1, wn = wid & 1;
  const int m0 = blockIdx.y * BM, n0 = blockIdx.x * 128;
  const int fr = lane & 15, fko = (lane >> 4) * 8;

  f4v acc[MF][4];
  #pragma unroll
  for (int i = 0; i < MF; i++)
    #pragma unroll
    for (int j = 0; j < 4; j++) acc[i][j] = (f4v){0.f, 0.f, 0.f, 0.f};

  const int steps = Kp >> 6;
  s8v ra[AU], rb[4];
  const s8v zed = (s8v){0,0,0,0,0,0,0,0};

  int arow[AU], akseg[AU], brow[4], bkseg[4];
  #pragma unroll
  for (int i = 0; i < AU; i++) { int gx = tid*AU + i; arow[i] = gx >> 3; akseg[i] = (gx & 7) * 8; }
  #pragma unroll
  for (int i = 0; i < 4; i++) { int gx = tid*4 + i; brow[i] = gx >> 3; bkseg[i] = (gx & 7) * 8; }

  // stage step 0
  #pragma unroll
  for (int i = 0; i < AU; i++)
    ra[i] = (m0 + arow[i] < M) ? *(const s8v*)(g.A + (size_t)(m0 + arow[i])*Kp + akseg[i]) : zed;
  #pragma unroll
  for (int i = 0; i < 4; i++)
    rb[i] = *(const s8v*)(g.B + (size_t)(n0 + brow[i])*Kp + bkseg[i]);
  #pragma unroll
  for (int i = 0; i < AU; i++) *(s8v*)&As[0][arow[i]*72 + akseg[i]] = ra[i];
  #pragma unroll
  for (int i = 0; i < 4; i++)  *(s8v*)&Bs[0][brow[i]*72 + bkseg[i]] = rb[i];
  __syncthreads();

  for (int s = 0; s < steps; s++) {
    if (s + 1 < steps) {
      const int ko = (s + 1) * 64;
      #pragma unroll
      for (int i = 0; i < AU; i++)
        ra[i] = (m0 + arow[i] < M) ? *(const s8v*)(g.A + (size_t)(m0 + arow[i])*Kp + ko + akseg[i]) : zed;
      #pragma unroll
      for (int i = 0; i < 4; i++)
        rb[i] = *(const s8v*)(g.B + (size_t)(n0 + brow[i])*Kp + ko + bkseg[i]);
    }
    const int buf = s & 1;
    #pragma unroll
    for (int kk = 0; kk < 2; kk++) {
      s8v af[MF], bfr[4];
      #pragma unroll
      for (int mm = 0; mm < MF; mm++)
        af[mm] = *(const s8v*)&As[buf][(wm*(BM/2) + mm*16 + fr)*72 + kk*32 + fko];
      #pragma unroll
      for (int nn = 0; nn < 4; nn++)
        bfr[nn] = *(const s8v*)&Bs[buf][(wn*64 + nn*16 + fr)*72 + kk*32 + fko];
      #pragma unroll
      for (int mm = 0; mm < MF; mm++)
        #pragma unroll
        for (int nn = 0; nn < 4; nn++)
          acc[mm][nn] = __builtin_amdgcn_mfma_f32_16x16x32_bf16(af[mm], bfr[nn], acc[mm][nn], 0, 0, 0);
    }
    if (s + 1 < steps) {
      #pragma unroll
      for (int i = 0; i < AU; i++) *(s8v*)&As[buf^1][arow[i]*72 + akseg[i]] = ra[i];
      #pragma unroll
      for (int i = 0; i < 4; i++)  *(s8v*)&Bs[buf^1][brow[i]*72 + bkseg[i]] = rb[i];
    }
    __syncthreads();
  }

  const bool kvm = (kvb != nullptr);
  #pragma unroll
  for (int mm = 0; mm < MF; mm++) {
    #pragma unroll
    for (int nn = 0; nn < 4; nn++) {
      const int col = n0 + wn*64 + nn*16 + fr;
      const int rb0 = m0 + wm*(BM/2) + mm*16 + (lane >> 4)*4;
      const float bc = kvm ? ((col < 512) ? kb0[col] : kb1[col - 512])
                           : (g.bias ? g.bias[col] : 0.f);
      #pragma unroll
      for (int q = 0; q < 4; q++) {
        const int r = rb0 + q;
        if (r >= M) continue;
        float v = acc[mm][nn][q] + bc;
        if (g.act == 1) v = fmaxf(v, 0.f);
        else if (g.act == 2) v = tanhf(v);
        if (g.res) v += b2f(g.res[(size_t)r*512 + col]);
        const unsigned short hv = f2b(v);
        if (kvm) {
          const int bb = r / 48, tt = r - bb*48;
          const int kvs = col >> 9, hh = (col >> 6) & 7, dd = col & 63;
          kvb[((((size_t)kvs*BN_ + bb)*8 + hh)*48 + tt)*64 + dd] = hv;
        } else {
          g.C[(size_t)r*512 + col] = hv;
        }
      }
    }
  }
}

// ============================================================
// Prep kernels: bf16 conversion / transposes / activations build
// ============================================================
__global__ void prep_evb(const float* __restrict__ enc, const float* __restrict__ tv,
                         unsigned short* __restrict__ evb)
{
  const int r = blockIdx.x;              // 0..31199
  const int bn = r / 48, t = r - bn * 48;
  for (int col = threadIdx.x; col < 448; col += 256) {
    unsigned short o = 0;
    if (col < 387) {
      const int v = col / 129, cc = col - v * 129;
      const float val = (cc < 128) ? enc[(((size_t)bn*3 + v)*48 + t)*128 + cc]
                                   : tv[((size_t)bn*3 + v)*48 + t];
      o = f2b(val);
    }
    evb[(size_t)r*448 + col] = o;
  }
}

__global__ void prep_attb(const float* __restrict__ enc, unsigned short* __restrict__ attb)
{
  const int r = blockIdx.x;              // 0..7799
  const int bn = r / 12, q = r - bn * 12;
  for (int col = threadIdx.x; col < 384; col += 256) {
    const int v = col >> 7, cc = col & 127;
    attb[(size_t)r*384 + col] = f2b(enc[(((size_t)bn*3 + v)*48 + 36 + q)*128 + cc]);
  }
}

__global__ void prep_wkv(const float* __restrict__ Wk, const float* __restrict__ Wv,
                         unsigned short* __restrict__ WT)
{
  const int l = blockIdx.y, n = blockIdx.x;            // n 0..1023
  const int kvs = n >> 9, h = (n >> 6) & 7, d = n & 63;
  const float* src = (kvs ? Wv : Wk) + ((size_t)(l*8 + h)*387)*64 + d;
  unsigned short* dst = WT + ((size_t)l*1024 + n)*448;
  for (int k = threadIdx.x; k < 448; k += 256)
    dst[k] = (k < 387) ? f2b(src[(size_t)k*64]) : 0;
}

__global__ void prep_wsh(const float* __restrict__ W, unsigned short* __restrict__ WT)
{
  const int n = blockIdx.x;                            // 0..511
  for (int k = threadIdx.x; k < 384; k += 256)
    WT[(size_t)n*384 + k] = f2b(W[(size_t)k*512 + n]);
}

__global__ void prep_wff(const float* __restrict__ W1, const float* __restrict__ W2,
                         unsigned short* __restrict__ T1, unsigned short* __restrict__ T2b)
{
  const int n = blockIdx.x, l = blockIdx.y, which = blockIdx.z;
  const float* src = (which ? W2 : W1) + (size_t)l*512*512;
  unsigned short* dst = (which ? T2b : T1) + ((size_t)l*512 + n)*512;
  for (int k = threadIdx.x; k < 512; k += 256)
    dst[k] = f2b(src[(size_t)k*512 + n]);
}

__global__ void prep_wnvp_in(const float* __restrict__ Ws, const float* __restrict__ Wt,
                             unsigned short* __restrict__ Ts, unsigned short* __restrict__ Tt)
{
  const int n = blockIdx.x, blk = blockIdx.y, net = blockIdx.z;
  const float* src = (net ? Wt : Ws) + (size_t)blk*515*512;
  unsigned short* dst = (net ? Tt : Ts) + ((size_t)blk*512 + n)*576;
  for (int k = threadIdx.x; k < 576; k += 256)
    dst[k] = (k < 515) ? f2b(src[(size_t)k*512 + n]) : 0;
}

__global__ void prep_wnvp_hid(const float* __restrict__ Ws, const float* __restrict__ Wt,
                              unsigned short* __restrict__ Ts, unsigned short* __restrict__ Tt)
{
  const int n = blockIdx.x, bi = blockIdx.y, net = blockIdx.z;   // bi = blk*4+i, 0..23
  const float* src = (net ? Wt : Ws) + (size_t)bi*512*512;
  unsigned short* dst = (net ? Tt : Ts) + ((size_t)bi*512 + n)*512;
  for (int k = threadIdx.x; k < 512; k += 256)
    dst[k] = f2b(src[(size_t)k*512 + n]);
}

__global__ void pad_ab_kernel(unsigned short* __restrict__ ab)
{
  const int r = blockIdx.x;
  if (threadIdx.x < 64) ab[(size_t)r*576 + 512 + threadIdx.x] = 0;
}

__global__ void zero_stats_kernel(float* __restrict__ sraw)
{
  const int i = blockIdx.x * blockDim.x + threadIdx.x;
  if (i < 6*36*2) sraw[i] = 0.f;
}

// ============================================================
// Attention + LN1 (fp32, per-bn workgroup)
// ============================================================
__global__ __launch_bounds__(256)
void attn_kernel(const unsigned short* __restrict__ avb, const unsigned short* __restrict__ kvb,
                 const float* __restrict__ lns, const float* __restrict__ lnb,
                 unsigned short* __restrict__ av2b)
{
  const int b = blockIdx.x, tid = threadIdx.x;
  __shared__ float av[12][520];
  __shared__ float att[12][520];
  __shared__ float kh[48][65];
  __shared__ float vh[48][65];
  __shared__ float sc[12][48];

  for (int idx = tid; idx < 12*512; idx += 256) {
    const int v = idx >> 9, c = idx & 511;
    av[v][c] = b2f(avb[((size_t)b*12 + v)*512 + c]);
    att[v][c] = 0.f;
  }
  const size_t kvhalf = (size_t)BN_*8*48*64;
  for (int h = 0; h < 8; h++) {
    __syncthreads();
    for (int idx = tid; idx < 48*64; idx += 256) {
      const int t = idx >> 6, d = idx & 63;
      const size_t o = (((size_t)b*8 + h)*48 + t)*64 + d;
      kh[t][d] = b2f(kvb[o]);
      vh[t][d] = b2f(kvb[kvhalf + o]);
    }
    __syncthreads();
    for (int idx = tid; idx < 576; idx += 256) {
      const int v = idx / 48, w = idx - v*48;
      float s = -1e30f;
      if (w < 36 + v) {
        s = 0.f;
        const float* ap = &av[v][h*64];
        #pragma unroll 8
        for (int i = 0; i < 64; i++) s = fmaf(ap[i], kh[w][i], s);
        s *= 0.125f;
      }
      sc[v][w] = s;
    }
    __syncthreads();
    if (tid < 12) {
      const int v = tid, nvv = 36 + v;
      float mx = -1e30f;
      for (int w = 0; w < nvv; w++) mx = fmaxf(mx, sc[v][w]);
      float sum = 0.f;
      for (int w = 0; w < nvv; w++) { const float p = expf(sc[v][w] - mx); sc[v][w] = p; sum += p; }
      const float inv = 1.f / sum;
      for (int w = 0; w < nvv; w++) sc[v][w] *= inv;
      for (int w = nvv; w < 48; w++) sc[v][w] = 0.f;
    }
    __syncthreads();
    for (int idx = tid; idx < 12*64; idx += 256) {
      const int v = idx >> 6, d = idx & 63;
      float a = 0.f;
      #pragma unroll 8
      for (int w = 0; w < 48; w++) a = fmaf(sc[v][w], vh[w][d], a);
      att[v][h*64 + d] = a;
    }
  }
  __syncthreads();
  // LN1: av2 = LN(av + att)
  const int lane = tid & 63, wv = tid >> 6;
  for (int v = wv; v < 12; v += 4) {
    float x[8], sm = 0.f, s2 = 0.f;
    #pragma unroll
    for (int j = 0; j < 8; j++) {
      const int c = lane*8 + j;
      const float t = av[v][c] + att[v][c];
      x[j] = t; sm += t; s2 += t*t;
    }
    #pragma unroll
    for (int o = 32; o; o >>= 1) { sm += __shfl_xor(sm, o); s2 += __shfl_xor(s2, o); }
    const float mean = sm * (1.f/512.f);
    const float var  = s2 * (1.f/512.f) - mean*mean;
    const float rr = rsqrtf(var + 1e-5f);
    #pragma unroll
    for (int j = 0; j < 8; j++) {
      const int c = lane*8 + j;
      av2b[((size_t)b*12 + v)*512 + c] = f2b((x[j] - mean)*rr*lns[c] + lnb[c]);
    }
  }
}

// LN over bf16 rows [7800][512] -> out with stride ldo
__global__ __launch_bounds__(256)
void ln_kernel(const unsigned short* __restrict__ in, unsigned short* __restrict__ out, int ldo,
               const float* __restrict__ s, const float* __restrict__ b)
{
  const int row = blockIdx.x*4 + (threadIdx.x >> 6);
  const int lane = threadIdx.x & 63;
  const s8v xv = *(const s8v*)(in + (size_t)row*512 + lane*8);
  float x[8], sm = 0.f, s2 = 0.f;
  #pragma unroll
  for (int j = 0; j < 8; j++) {
    const float t = b2f((unsigned short)xv[j]);
    x[j] = t; sm += t; s2 += t*t;
  }
  #pragma unroll
  for (int o = 32; o; o >>= 1) { sm += __shfl_xor(sm, o); s2 += __shfl_xor(s2, o); }
  const float mean = sm * (1.f/512.f);
  const float var  = s2 * (1.f/512.f) - mean*mean;
  const float rr = rsqrtf(var + 1e-5f);
  s8v o8;
  #pragma unroll
  for (int j = 0; j < 8; j++) {
    const int c = lane*8 + j;
    o8[j] = (short)f2b((x[j] - mean)*rr*s[c] + b[c]);
  }
  *(s8v*)(out + (size_t)row*ldo + lane*8) = o8;
}

// ============================================================
// NVP small kernels
// ============================================================
__global__ void mu_kernel(const float* __restrict__ tv, const float* __restrict__ u,
                          const float* __restrict__ sab, float* __restrict__ uinf,
                          unsigned short* __restrict__ ab, int blk)
{
  const int r = blockIdx.x*256 + threadIdx.x;
  if (r >= NROWS_) return;
  const int bn = r / 12, q = r - bn * 12;
  float uv[3];
  #pragma unroll
  for (int v = 0; v < 3; v++) {
    if (blk == 0) uv[v] = tv[((size_t)bn*3 + v)*48 + 36 + q];
    else {
      const float a = sab[((blk-1)*36 + q*3 + v)*2 + 0];
      const float c = sab[((blk-1)*36 + q*3 + v)*2 + 1];
      uv[v] = fmaf(a, u[(size_t)r*3 + v], c);
    }
  }
  #pragma unroll
  for (int v = 0; v < 3; v++) {
    uinf[(size_t)r*3 + v] = uv[v];
    ab[(size_t)r*576 + 512 + v] = f2b(((v + blk) & 1) ? uv[v] : 0.f);
  }
}

__global__ __launch_bounds__(256)
void out_kernel(const unsigned short* __restrict__ hs, const unsigned short* __restrict__ ht,
                const float* __restrict__ swo, const float* __restrict__ sbo,
                const float* __restrict__ two, const float* __restrict__ tbo,
                float* __restrict__ souts, int blk)
{
  const int gw = (blockIdx.x*256 + threadIdx.x) >> 6;
  const int lane = threadIdx.x & 63;
  const int r = gw >> 1, net = gw & 1;
  if (r >= NROWS_) return;
  const unsigned short* h = (net ? ht : hs) + (size_t)r*512;
  const float* wo = (net ? two : swo) + (size_t)blk*512*3;
  float a0 = 0.f, a1 = 0.f, a2 = 0.f;
  for (int k = lane; k < 512; k += 64) {
    const float hv = b2f(h[k]);
    a0 = fmaf(hv, wo[k*3+0], a0);
    a1 = fmaf(hv, wo[k*3+1], a1);
    a2 = fmaf(hv, wo[k*3+2], a2);
  }
  #pragma unroll
  for (int o = 32; o; o >>= 1) {
    a0 += __shfl_xor(a0, o); a1 += __shfl_xor(a1, o); a2 += __shfl_xor(a2, o);
  }
  if (lane == 0) {
    const float* bo = (net ? tbo : sbo) + blk*3;
    souts[((size_t)r*2 + net)*3 + 0] = a0 + bo[0];
    souts[((size_t)r*2 + net)*3 + 1] = a1 + bo[1];
    souts[((size_t)r*2 + net)*3 + 2] = a2 + bo[2];
  }
}

__global__ void couple_kernel(const float* __restrict__ souts, const float* __restrict__ uinf,
                              float* __restrict__ u, float* __restrict__ ld,
                              float* __restrict__ sraw, int blk)
{
  const int r = blockIdx.x*256 + threadIdx.x;
  if (r >= NROWS_) return;
  const int q = r % 12;
  #pragma unroll
  for (int j = 0; j < 3; j++) {
    const int msk = (j + blk) & 1;
    const float s = souts[((size_t)r*2 + 0)*3 + j];
    const float t = souts[((size_t)r*2 + 1)*3 + j];
    const float uo = uinf[(size_t)r*3 + j];
    const float unew = msk ? uo : (uo - t) * expf(-s);
    u[(size_t)r*3 + j] = unew;
    const float prev = blk ? ld[(size_t)r*3 + j] : 0.f;
    ld[(size_t)r*3 + j] = prev - (msk ? 0.f : s);
    atomicAdd(&sraw[(blk*36 + q*3 + j)*2 + 0], unew);
    atomicAdd(&sraw[(blk*36 + q*3 + j)*2 + 1], unew * unew);
  }
}

__global__ void bn_finalize_kernel(const float* __restrict__ sraw, float* __restrict__ sab,
    float* __restrict__ ldadd, const float* __restrict__ lg, const float* __restrict__ bt, int blk)
{
  const int idx = threadIdx.x;
  if (idx < 36) {
    const int v = idx % 3;
    const float sum = sraw[(blk*36 + idx)*2 + 0];
    const float s2  = sraw[(blk*36 + idx)*2 + 1];
    const float bm  = sum * (1.f / 650.f);
    const float bvr = s2 * (1.f / 650.f) - bm * bm;
    const float g = lg[blk*3 + v];
    const float a = expf(g) * rsqrtf(bvr + 1e-5f);
    sab[(blk*36 + idx)*2 + 0] = a;
    sab[(blk*36 + idx)*2 + 1] = bt[blk*3 + v] - a * bm;
    ldadd[blk*36 + idx] = g - 0.5f * logf(bvr + 1e-5f);
  }
}

__global__ void loss_kernel(const float* __restrict__ u, const float* __restrict__ ld,
    const float* __restrict__ sab, const float* __restrict__ ldadd, float* __restrict__ out)
{
  const int bn = blockIdx.x * blockDim.x + threadIdx.x;
  if (bn >= BN_) return;
  float acc = 0.f;
  for (int t2 = 0; t2 < 12; t2++) {
    #pragma unroll
    for (int v = 0; v < 3; v++) {
      const int idx = t2*3 + v;
      const float a = sab[(5*36 + idx)*2 + 0];
      const float c = sab[(5*36 + idx)*2 + 1];
      const float ur = u[((size_t)bn*12 + t2)*3 + v];
      const float ub = fmaf(a, ur, c);
      acc += 0.5f*ub*ub + 0.5f*LOG2PI_ - ld[((size_t)bn*12 + t2)*3 + v];
    }
  }
  float lsum = 0.f;
  for (int i = 0; i < 6*36; i++) lsum += ldadd[i];
  out[bn] = acc - lsum;
}

// ============================================================
// workspace byte offsets
// ============================================================
#define O_WKV    (size_t)0
#define O_WSH    (size_t)3670016
#define O_WFF1   (size_t)4063232
#define O_WFF2   (size_t)6160384
#define O_WSIN   (size_t)8257536
#define O_WTIN   (size_t)11796480
#define O_WSHID  (size_t)15335424
#define O_WTHID  (size_t)27918336
#define O_EVB    (size_t)40501248
#define O_ATTB   (size_t)68456448
#define O_AVB    (size_t)74446848
#define O_AV2B   (size_t)82434048
#define O_HB     (size_t)90421248
#define O_FFSUM  (size_t)98408448
#define O_KVB    (size_t)106395648
#define O_AB     O_KVB
#define O_HS0    (O_KVB + 8985600)
#define O_HS1    (O_HS0 + 7987200)
#define O_HT0    (O_HS1 + 7987200)
#define O_HT1    (O_HT0 + 7987200)
#define O_UINF   (size_t)170293248
#define O_U      (size_t)170386848
#define O_LD     (size_t)170480448
#define O_SOUTS  (size_t)170574048
#define O_SRAW   (size_t)170761248
#define O_SAB    (size_t)170762976
#define O_LDA    (size_t)170764704

static inline GZ mkgz(const void* A, const void* B, const float* bias, void* C,
                      const void* res, int act) {
  GZ g; g.A = (const unsigned short*)A; g.B = (const unsigned short*)B; g.bias = bias;
  g.C = (unsigned short*)C; g.res = (const unsigned short*)res; g.act = act; return g;
}

extern "C" void kernel_launch(void* const* d_in, const int* in_sizes, int n_in,
                              void* d_out, int out_size, void* d_ws, size_t ws_size,
                              hipStream_t stream)
{
  const float* enc   = (const float*)d_in[0];
  const float* tv    = (const float*)d_in[1];
  const float* Wsh   = (const float*)d_in[2];
  const float* bsh   = (const float*)d_in[3];
  const float* Wk    = (const float*)d_in[4];
  const float* bk    = (const float*)d_in[5];
  const float* Wv    = (const float*)d_in[6];
  const float* bv    = (const float*)d_in[7];
  const float* ln1s  = (const float*)d_in[8];
  const float* ln1b  = (const float*)d_in[9];
  const float* fw1   = (const float*)d_in[10];
  const float* fb1   = (const float*)d_in[11];
  const float* fw2   = (const float*)d_in[12];
  const float* fb2   = (const float*)d_in[13];
  const float* ln2s  = (const float*)d_in[14];
  const float* ln2b  = (const float*)d_in[15];
  const float* swin  = (const float*)d_in[16];
  const float* sbin  = (const float*)d_in[17];
  const float* swhid = (const float*)d_in[18];
  const float* sbhid = (const float*)d_in[19];
  const float* swout = (const float*)d_in[20];
  const float* sbout = (const float*)d_in[21];
  const float* twin  = (const float*)d_in[22];
  const float* tbin  = (const float*)d_in[23];
  const float* twhid = (const float*)d_in[24];
  const float* tbhid = (const float*)d_in[25];
  const float* twout = (const float*)d_in[26];
  const float* tbout = (const float*)d_in[27];
  const float* bnlg  = (const float*)d_in[28];
  const float* bnbt  = (const float*)d_in[29];

  char* ws = (char*)d_ws;
  unsigned short* wkv   = (unsigned short*)(ws + O_WKV);
  unsigned short* wsht  = (unsigned short*)(ws + O_WSH);
  unsigned short* wff1t = (unsigned short*)(ws + O_WFF1);
  unsigned short* wff2t = (unsigned short*)(ws + O_WFF2);
  unsigned short* wsint = (unsigned short*)(ws + O_WSIN);
  unsigned short* wtint = (unsigned short*)(ws + O_WTIN);
  unsigned short* wshid = (unsigned short*)(ws + O_WSHID);
  unsigned short* wthid = (unsigned short*)(ws + O_WTHID);
  unsigned short* evb   = (unsigned short*)(ws + O_EVB);
  unsigned short* attb  = (unsigned short*)(ws + O_ATTB);
  unsigned short* avb   = (unsigned short*)(ws + O_AVB);
  unsigned short* av2b  = (unsigned short*)(ws + O_AV2B);
  unsigned short* hb    = (unsigned short*)(ws + O_HB);
  unsigned short* ffsum = (unsigned short*)(ws + O_FFSUM);
  unsigned short* kvb   = (unsigned short*)(ws + O_KVB);
  unsigned short* ab    = (unsigned short*)(ws + O_AB);
  unsigned short* hs0   = (unsigned short*)(ws + O_HS0);
  unsigned short* hs1   = (unsigned short*)(ws + O_HS1);
  unsigned short* ht0   = (unsigned short*)(ws + O_HT0);
  unsigned short* ht1   = (unsigned short*)(ws + O_HT1);
  float* uinf  = (float*)(ws + O_UINF);
  float* u     = (float*)(ws + O_U);
  float* ld    = (float*)(ws + O_LD);
  float* souts = (float*)(ws + O_SOUTS);
  float* sraw  = (float*)(ws + O_SRAW);
  float* sab   = (float*)(ws + O_SAB);
  float* lda   = (float*)(ws + O_LDA);
  float* out   = (float*)d_out;

  // ---- prep ----
  prep_evb<<<MKV_, 256, 0, stream>>>(enc, tv, evb);
  prep_attb<<<NROWS_, 256, 0, stream>>>(enc, attb);
  prep_wkv<<<dim3(1024, 4), 256, 0, stream>>>(Wk, Wv, wkv);
  prep_wsh<<<512, 256, 0, stream>>>(Wsh, wsht);
  prep_wff<<<dim3(512, 4, 2), 256, 0, stream>>>(fw1, fw2, wff1t, wff2t);
  prep_wnvp_in<<<dim3(512, 6, 2), 256, 0, stream>>>(swin, twin, wsint, wtint);
  prep_wnvp_hid<<<dim3(512, 24, 2), 256, 0, stream>>>(swhid, twhid, wshid, wthid);
  zero_stats_kernel<<<2, 256, 0, stream>>>(sraw);

  const GZ gnull = mkgz(nullptr, nullptr, nullptr, nullptr, nullptr, 0);

  // ---- shift GEMM: av0 = attb @ Wsh + bsh ----
  {
    GZ g = mkgz(attb, wsht, bsh, avb, nullptr, 0);
    gemm_bf16<64><<<dim3(4, 122, 1), 256, 0, stream>>>(g, gnull, NROWS_, 384,
        nullptr, nullptr, nullptr);
  }

  // ---- transformer layers ----
  for (int l = 0; l < 4; l++) {
    GZ g = mkgz(evb, wkv + (size_t)l*1024*448, nullptr, nullptr, nullptr, 0);
    gemm_bf16<128><<<dim3(8, 244, 1), 256, 0, stream>>>(g, gnull, MKV_, 448,
        kvb, bk + l*512, bv + l*512);
    attn_kernel<<<BN_, 256, 0, stream>>>(avb, kvb, ln1s + l*512, ln1b + l*512, av2b);
    GZ g1 = mkgz(av2b, wff1t + (size_t)l*512*512, fb1 + l*512, hb, nullptr, 1);
    gemm_bf16<64><<<dim3(4, 122, 1), 256, 0, stream>>>(g1, gnull, NROWS_, 512,
        nullptr, nullptr, nullptr);
    GZ g2 = mkgz(hb, wff2t + (size_t)l*512*512, fb2 + l*512, ffsum, av2b, 0);
    gemm_bf16<64><<<dim3(4, 122, 1), 256, 0, stream>>>(g2, gnull, NROWS_, 512,
        nullptr, nullptr, nullptr);
    if (l == 3)
      ln_kernel<<<1950, 256, 0, stream>>>(ffsum, ab, 576, ln2s + l*512, ln2b + l*512);
    else
      ln_kernel<<<1950, 256, 0, stream>>>(ffsum, avb, 512, ln2s + l*512, ln2b + l*512);
  }

  // ---- RealNVP ----
  pad_ab_kernel<<<NROWS_, 64, 0, stream>>>(ab);
  for (int blk = 0; blk < 6; blk++) {
    mu_kernel<<<31, 256, 0, stream>>>(tv, u, sab, uinf, ab, blk);
    {
      GZ gs = mkgz(ab, wsint + (size_t)blk*512*576, sbin + blk*512, hs0, nullptr, 2);
      GZ gt = mkgz(ab, wtint + (size_t)blk*512*576, tbin + blk*512, ht0, nullptr, 1);
      gemm_bf16<64><<<dim3(4, 122, 2), 256, 0, stream>>>(gs, gt, NROWS_, 576,
          nullptr, nullptr, nullptr);
    }
    for (int i = 0; i < 4; i++) {
      unsigned short* srcs = (i & 1) ? hs1 : hs0;
      unsigned short* dsts = (i & 1) ? hs0 : hs1;
      unsigned short* srct = (i & 1) ? ht1 : ht0;
      unsigned short* dstt = (i & 1) ? ht0 : ht1;
      GZ gs = mkgz(srcs, wshid + (size_t)(blk*4 + i)*512*512, sbhid + (blk*4 + i)*512, dsts, nullptr, 2);
      GZ gt = mkgz(srct, wthid + (size_t)(blk*4 + i)*512*512, tbhid + (blk*4 + i)*512, dstt, nullptr, 1);
      gemm_bf16<64><<<dim3(4, 122, 2), 256, 0, stream>>>(gs, gt, NROWS_, 512,
          nullptr, nullptr, nullptr);
    }
    out_kernel<<<3900, 256, 0, stream>>>(hs0, ht0, swout, sbout, twout, tbout, souts, blk);
    couple_kernel<<<31, 256, 0, stream>>>(souts, uinf, u, ld, sraw, blk);
    bn_finalize_kernel<<<1, 64, 0, stream>>>(sraw, sab, lda, bnlg, bnbt, blk);
  }
  loss_kernel<<<3, 256, 0, stream>>>(u, ld, sab, lda, out);
}

// Round 4
// 2745.835 us; speedup vs baseline: 4.8924x; 1.2543x over previous
//
#include <hip/hip_runtime.h>
#include <math.h>

// ---- problem dims ----
#define BN_ 650
#define T_ 48
#define V_ 3
#define T2_ 12
#define NROWS_ 7800            // BN_*T2_
#define MKV_ 31200             // BN_*T_
#define LOG2PI_ 1.8378770664093453f

typedef short s8v __attribute__((ext_vector_type(8)));
typedef float f4v __attribute__((ext_vector_type(4)));

__device__ __forceinline__ float b2f(unsigned short h) {
  return __uint_as_float(((unsigned)h) << 16);
}
__device__ __forceinline__ unsigned short f2b(float f) {
  unsigned u = __float_as_uint(f);
  return (unsigned short)((u + 0x7fffu + ((u >> 16) & 1u)) >> 16);
}

// ============================================================
// Canonical bf16 MFMA GEMM: C[M,N] = act(A[M,Kp] @ BT[N,Kp]^T + bias) (+res)
// BT is pre-transposed [N][Kp] bf16. Tile: BM x 128, 256 thr, 4 waves (2x2).
// ============================================================
struct GZ {
  const unsigned short* A;
  const unsigned short* B;
  const float* bias;
  unsigned short* C;
  const unsigned short* res;
  int act;   // 0 none, 1 relu, 2 tanh
};

template<int BM>
__global__ __launch_bounds__(256)
void gemm_bf16(GZ g0, GZ g1, int M, int Kp,
               unsigned short* __restrict__ kvb,
               const float* __restrict__ kb0, const float* __restrict__ kb1)
{
  constexpr int MF = BM / 32;      // m-frags per wave
  constexpr int AU = BM / 32;      // A b128 units per thread
  __shared__ __align__(16) unsigned short As[2][BM * 72];
  __shared__ __align__(16) unsigned short Bs[2][128 * 72];
  GZ g = (blockIdx.z == 0) ? g0 : g1;
  const int tid = threadIdx.x;
  const int lane = tid & 63;
  const int wid = tid >> 6;
  const int wm = wid >> 1, wn = wid & 1;
  const int m0 = blockIdx.y * BM, n0 = blockIdx.x * 128;
  const int fr = lane & 15, fko = (lane >> 4) * 8;

  f4v acc[MF][4];
  #pragma unroll
  for (int i = 0; i < MF; i++)
    #pragma unroll
    for (int j = 0; j < 4; j++) acc[i][j] = (f4v){0.f, 0.f, 0.f, 0.f};

  const int steps = Kp >> 6;
  s8v ra[AU], rb[4];
  const s8v zed = (s8v){0,0,0,0,0,0,0,0};

  int arow[AU], akseg[AU], brow[4], bkseg[4];
  #pragma unroll
  for (int i = 0; i < AU; i++) { int gx = tid*AU + i; arow[i] = gx >> 3; akseg[i] = (gx & 7) * 8; }
  #pragma unroll
  for (int i = 0; i < 4; i++) { int gx = tid*4 + i; brow[i] = gx >> 3; bkseg[i] = (gx & 7) * 8; }

  // stage step 0
  #pragma unroll
  for (int i = 0; i < AU; i++)
    ra[i] = (m0 + arow[i] < M) ? *(const s8v*)(g.A + (size_t)(m0 + arow[i])*Kp + akseg[i]) : zed;
  #pragma unroll
  for (int i = 0; i < 4; i++)
    rb[i] = *(const s8v*)(g.B + (size_t)(n0 + brow[i])*Kp + bkseg[i]);
  #pragma unroll
  for (int i = 0; i < AU; i++) *(s8v*)&As[0][arow[i]*72 + akseg[i]] = ra[i];
  #pragma unroll
  for (int i = 0; i < 4; i++)  *(s8v*)&Bs[0][brow[i]*72 + bkseg[i]] = rb[i];
  __syncthreads();

  for (int s = 0; s < steps; s++) {
    if (s + 1 < steps) {
      const int ko = (s + 1) * 64;
      #pragma unroll
      for (int i = 0; i < AU; i++)
        ra[i] = (m0 + arow[i] < M) ? *(const s8v*)(g.A + (size_t)(m0 + arow[i])*Kp + ko + akseg[i]) : zed;
      #pragma unroll
      for (int i = 0; i < 4; i++)
        rb[i] = *(const s8v*)(g.B + (size_t)(n0 + brow[i])*Kp + ko + bkseg[i]);
    }
    const int buf = s & 1;
    #pragma unroll
    for (int kk = 0; kk < 2; kk++) {
      s8v af[MF], bfr[4];
      #pragma unroll
      for (int mm = 0; mm < MF; mm++)
        af[mm] = *(const s8v*)&As[buf][(wm*(BM/2) + mm*16 + fr)*72 + kk*32 + fko];
      #pragma unroll
      for (int nn = 0; nn < 4; nn++)
        bfr[nn] = *(const s8v*)&Bs[buf][(wn*64 + nn*16 + fr)*72 + kk*32 + fko];
      #pragma unroll
      for (int mm = 0; mm < MF; mm++)
        #pragma unroll
        for (int nn = 0; nn < 4; nn++)
          acc[mm][nn] = __builtin_amdgcn_mfma_f32_16x16x32_bf16(af[mm], bfr[nn], acc[mm][nn], 0, 0, 0);
    }
    if (s + 1 < steps) {
      #pragma unroll
      for (int i = 0; i < AU; i++) *(s8v*)&As[buf^1][arow[i]*72 + akseg[i]] = ra[i];
      #pragma unroll
      for (int i = 0; i < 4; i++)  *(s8v*)&Bs[buf^1][brow[i]*72 + bkseg[i]] = rb[i];
    }
    __syncthreads();
  }

  const bool kvm = (kvb != nullptr);
  #pragma unroll
  for (int mm = 0; mm < MF; mm++) {
    #pragma unroll
    for (int nn = 0; nn < 4; nn++) {
      const int col = n0 + wn*64 + nn*16 + fr;
      const int rb0 = m0 + wm*(BM/2) + mm*16 + (lane >> 4)*4;
      const float bc = kvm ? ((col < 512) ? kb0[col] : kb1[col - 512])
                           : (g.bias ? g.bias[col] : 0.f);
      #pragma unroll
      for (int q = 0; q < 4; q++) {
        const int r = rb0 + q;
        if (r >= M) continue;
        float v = acc[mm][nn][q] + bc;
        if (g.act == 1) v = fmaxf(v, 0.f);
        else if (g.act == 2) v = tanhf(v);
        if (g.res) v += b2f(g.res[(size_t)r*512 + col]);
        const unsigned short hv = f2b(v);
        if (kvm) {
          const int bb = r / 48, tt = r - bb*48;
          const int kvs = col >> 9, hh = (col >> 6) & 7, dd = col & 63;
          // K: [b][h][t][d]; V: transposed [b][h][d][t] (for attn V-col reads)
          const size_t o = kvs ? ((((size_t)BN_ + bb)*8 + hh)*64 + dd)*48 + tt
                               : (((size_t)bb*8 + hh)*48 + tt)*64 + dd;
          kvb[o] = hv;
        } else {
          g.C[(size_t)r*512 + col] = hv;
        }
      }
    }
  }
}

// ============================================================
// Prep kernels
// ============================================================
__global__ void prep_evb(const float* __restrict__ enc, const float* __restrict__ tv,
                         unsigned short* __restrict__ evb)
{
  const int r = blockIdx.x;              // 0..31199
  const int bn = r / 48, t = r - bn * 48;
  for (int col = threadIdx.x; col < 448; col += 256) {
    unsigned short o = 0;
    if (col < 387) {
      const int v = col / 129, cc = col - v * 129;
      const float val = (cc < 128) ? enc[(((size_t)bn*3 + v)*48 + t)*128 + cc]
                                   : tv[((size_t)bn*3 + v)*48 + t];
      o = f2b(val);
    }
    evb[(size_t)r*448 + col] = o;
  }
}

__global__ void prep_attb(const float* __restrict__ enc, unsigned short* __restrict__ attb)
{
  const int r = blockIdx.x;              // 0..7799
  const int bn = r / 12, q = r - bn * 12;
  for (int col = threadIdx.x; col < 384; col += 256) {
    const int v = col >> 7, cc = col & 127;
    attb[(size_t)r*384 + col] = f2b(enc[(((size_t)bn*3 + v)*48 + 36 + q)*128 + cc]);
  }
}

__global__ void prep_wkv(const float* __restrict__ Wk, const float* __restrict__ Wv,
                         unsigned short* __restrict__ WT)
{
  const int l = blockIdx.y, n = blockIdx.x;            // n 0..1023
  const int kvs = n >> 9, h = (n >> 6) & 7, d = n & 63;
  const float* src = (kvs ? Wv : Wk) + ((size_t)(l*8 + h)*387)*64 + d;
  unsigned short* dst = WT + ((size_t)l*1024 + n)*448;
  for (int k = threadIdx.x; k < 448; k += 256)
    dst[k] = (k < 387) ? f2b(src[(size_t)k*64]) : 0;
}

__global__ void prep_wsh(const float* __restrict__ W, unsigned short* __restrict__ WT)
{
  const int n = blockIdx.x;                            // 0..511
  for (int k = threadIdx.x; k < 384; k += 256)
    WT[(size_t)n*384 + k] = f2b(W[(size_t)k*512 + n]);
}

__global__ void prep_wff(const float* __restrict__ W1, const float* __restrict__ W2,
                         unsigned short* __restrict__ T1, unsigned short* __restrict__ T2b)
{
  const int n = blockIdx.x, l = blockIdx.y, which = blockIdx.z;
  const float* src = (which ? W2 : W1) + (size_t)l*512*512;
  unsigned short* dst = (which ? T2b : T1) + ((size_t)l*512 + n)*512;
  for (int k = threadIdx.x; k < 512; k += 256)
    dst[k] = f2b(src[(size_t)k*512 + n]);
}

__global__ void prep_wnvp_in(const float* __restrict__ Ws, const float* __restrict__ Wt,
                             unsigned short* __restrict__ Ts, unsigned short* __restrict__ Tt)
{
  const int n = blockIdx.x, blk = blockIdx.y, net = blockIdx.z;
  const float* src = (net ? Wt : Ws) + (size_t)blk*515*512;
  unsigned short* dst = (net ? Tt : Ts) + ((size_t)blk*512 + n)*576;
  for (int k = threadIdx.x; k < 576; k += 256)
    dst[k] = (k < 515) ? f2b(src[(size_t)k*512 + n]) : 0;
}

__global__ void prep_wnvp_hid(const float* __restrict__ Ws, const float* __restrict__ Wt,
                              unsigned short* __restrict__ Ts, unsigned short* __restrict__ Tt)
{
  const int n = blockIdx.x, bi = blockIdx.y, net = blockIdx.z;   // bi = blk*4+i
  const float* src = (net ? Wt : Ws) + (size_t)bi*512*512;
  unsigned short* dst = (net ? Tt : Ts) + ((size_t)bi*512 + n)*512;
  for (int k = threadIdx.x; k < 512; k += 256)
    dst[k] = f2b(src[(size_t)k*512 + n]);
}

__global__ void pad_ab_kernel(unsigned short* __restrict__ ab)
{
  const int r = blockIdx.x;
  if (threadIdx.x < 64) ab[(size_t)r*576 + 512 + threadIdx.x] = 0;
}

__global__ void zero_stats_kernel(float* __restrict__ sraw)
{
  const int i = blockIdx.x * blockDim.x + threadIdx.x;
  if (i < 6*36*2) sraw[i] = 0.f;
}

// ============================================================
// Attention + LN1: 650 blocks x 512 thr; wave h owns head h.
// K rows per lane (lane=key t), Q broadcast from LDS, softmax via
// shfl_xor over 64 lanes, PV via shfl(p) with V^T cols per lane (lane=d).
// ============================================================
__global__ __launch_bounds__(512)
void attn_kernel(const unsigned short* __restrict__ avb, const unsigned short* __restrict__ kvb,
                 const float* __restrict__ lns, const float* __restrict__ lnb,
                 unsigned short* __restrict__ av2b)
{
  const int b = blockIdx.x, tid = threadIdx.x;
  const int h = tid >> 6, lane = tid & 63;
  __shared__ float av [12][516];
  __shared__ float att[12][516];

  // cooperative load av rows to fp32 LDS: 768 s8v chunks
  for (int idx = tid; idx < 12*64; idx += 512) {
    const int v = idx >> 6, c8 = idx & 63;
    const s8v a8 = *(const s8v*)(avb + (((size_t)b*12 + v) << 9) + c8*8);
    #pragma unroll
    for (int j = 0; j < 8; j++) av[v][c8*8 + j] = b2f((unsigned short)a8[j]);
  }
  __syncthreads();

  // K row (lane = key t, clamped), packed bf16
  const int tcl = (lane < 48) ? lane : 0;
  s8v kp[8];
  {
    const unsigned short* kr = kvb + (((size_t)b*8 + h)*48 + tcl)*64;
    #pragma unroll
    for (int i = 0; i < 8; i++) kp[i] = *(const s8v*)(kr + i*8);
  }
  // V^T col (lane = d), packed bf16
  s8v vp[6];
  {
    const unsigned short* vr = kvb + ((((size_t)BN_ + b)*8 + h)*64 + lane)*48;
    #pragma unroll
    for (int i = 0; i < 6; i++) vp[i] = *(const s8v*)(vr + i*8);
  }

  // ---- scores: p[v] = Q[v] . K[lane] ----
  float p[12];
  #pragma unroll
  for (int v = 0; v < 12; v++) p[v] = 0.f;
  #pragma unroll
  for (int k8 = 0; k8 < 8; k8++) {
    float kf[8];
    #pragma unroll
    for (int j = 0; j < 8; j++) kf[j] = b2f((unsigned short)kp[k8][j]);
    #pragma unroll
    for (int v = 0; v < 12; v++) {
      const float* qp = &av[v][h*64 + k8*8];
      #pragma unroll
      for (int j = 0; j < 8; j++) p[v] = fmaf(qp[j], kf[j], p[v]);
    }
  }
  // ---- softmax over keys (lanes), mask: key t valid iff t < 36+v ----
  #pragma unroll
  for (int v = 0; v < 12; v++) {
    const bool valid = (lane < 36 + v);
    float s = valid ? p[v]*0.125f : -1e30f;
    float m = s;
    #pragma unroll
    for (int off = 1; off < 64; off <<= 1) m = fmaxf(m, __shfl_xor(m, off));
    const float e = valid ? expf(s - m) : 0.f;
    float sum = e;
    #pragma unroll
    for (int off = 1; off < 64; off <<= 1) sum += __shfl_xor(sum, off);
    p[v] = e / sum;
  }
  // ---- PV: lane = d; o[v] = sum_t p[v][t] * V[t][d] ----
  float o[12];
  #pragma unroll
  for (int v = 0; v < 12; v++) o[v] = 0.f;
  #pragma unroll
  for (int t6 = 0; t6 < 6; t6++) {
    float vf[8];
    #pragma unroll
    for (int j = 0; j < 8; j++) vf[j] = b2f((unsigned short)vp[t6][j]);
    #pragma unroll
    for (int j = 0; j < 8; j++) {
      const int tt = t6*8 + j;
      #pragma unroll
      for (int v = 0; v < 12; v++) o[v] = fmaf(__shfl(p[v], tt), vf[j], o[v]);
    }
  }
  #pragma unroll
  for (int v = 0; v < 12; v++) att[v][h*64 + lane] = o[v];
  __syncthreads();

  // ---- LN1: av2 = LN(av + att) ----
  for (int v = h; v < 12; v += 8) {
    float x[8], sm = 0.f, s2 = 0.f;
    #pragma unroll
    for (int j = 0; j < 8; j++) {
      const int c = lane*8 + j;
      const float t = av[v][c] + att[v][c];
      x[j] = t; sm += t; s2 += t*t;
    }
    #pragma unroll
    for (int off = 32; off; off >>= 1) { sm += __shfl_xor(sm, off); s2 += __shfl_xor(s2, off); }
    const float mean = sm * (1.f/512.f);
    const float var  = s2 * (1.f/512.f) - mean*mean;
    const float rr = rsqrtf(var + 1e-5f);
    #pragma unroll
    for (int j = 0; j < 8; j++) {
      const int c = lane*8 + j;
      av2b[(((size_t)b*12 + v) << 9) + c] = f2b((x[j] - mean)*rr*lns[c] + lnb[c]);
    }
  }
}

// LN over bf16 rows [7800][512] -> out with stride ldo
__global__ __launch_bounds__(256)
void ln_kernel(const unsigned short* __restrict__ in, unsigned short* __restrict__ out, int ldo,
               const float* __restrict__ s, const float* __restrict__ b)
{
  const int row = blockIdx.x*4 + (threadIdx.x >> 6);
  const int lane = threadIdx.x & 63;
  const s8v xv = *(const s8v*)(in + (size_t)row*512 + lane*8);
  float x[8], sm = 0.f, s2 = 0.f;
  #pragma unroll
  for (int j = 0; j < 8; j++) {
    const float t = b2f((unsigned short)xv[j]);
    x[j] = t; sm += t; s2 += t*t;
  }
  #pragma unroll
  for (int o = 32; o; o >>= 1) { sm += __shfl_xor(sm, o); s2 += __shfl_xor(s2, o); }
  const float mean = sm * (1.f/512.f);
  const float var  = s2 * (1.f/512.f) - mean*mean;
  const float rr = rsqrtf(var + 1e-5f);
  s8v o8;
  #pragma unroll
  for (int j = 0; j < 8; j++) {
    const int c = lane*8 + j;
    o8[j] = (short)f2b((x[j] - mean)*rr*s[c] + b[c]);
  }
  *(s8v*)(out + (size_t)row*ldo + lane*8) = o8;
}

// ============================================================
// NVP small kernels
// ============================================================
__global__ void mu_kernel(const float* __restrict__ tv, const float* __restrict__ u,
                          const float* __restrict__ sab, float* __restrict__ uinf,
                          unsigned short* __restrict__ ab, int blk)
{
  const int r = blockIdx.x*256 + threadIdx.x;
  if (r >= NROWS_) return;
  const int bn = r / 12, q = r - bn * 12;
  float uv[3];
  #pragma unroll
  for (int v = 0; v < 3; v++) {
    if (blk == 0) uv[v] = tv[((size_t)bn*3 + v)*48 + 36 + q];
    else {
      const float a = sab[((blk-1)*36 + q*3 + v)*2 + 0];
      const float c = sab[((blk-1)*36 + q*3 + v)*2 + 1];
      uv[v] = fmaf(a, u[(size_t)r*3 + v], c);
    }
  }
  #pragma unroll
  for (int v = 0; v < 3; v++) {
    uinf[(size_t)r*3 + v] = uv[v];
    ab[(size_t)r*576 + 512 + v] = f2b(((v + blk) & 1) ? uv[v] : 0.f);
  }
}

// out-layer (s and t nets) + coupling update + stats, fused.
// 1950 blocks x 512 thr: wave w -> (row base+w/2, net w&1)
__global__ __launch_bounds__(512)
void out_couple_kernel(const unsigned short* __restrict__ hs, const unsigned short* __restrict__ ht,
                const float* __restrict__ swo, const float* __restrict__ sbo,
                const float* __restrict__ two, const float* __restrict__ tbo,
                const float* __restrict__ uinf, float* __restrict__ u, float* __restrict__ ld,
                float* __restrict__ sraw, int blk)
{
  __shared__ float sres[4][2][3];
  const int tid = threadIdx.x;
  const int w = tid >> 6, lane = tid & 63;
  const int rloc = w >> 1, net = w & 1;
  const int r = blockIdx.x*4 + rloc;
  const unsigned short* hrow = (net ? ht : hs) + ((size_t)r << 9);
  const float* wo = (net ? two : swo) + (size_t)blk*512*3;

  const s8v hv8 = *(const s8v*)(hrow + lane*8);
  float wbuf[24];
  #pragma unroll
  for (int i = 0; i < 6; i++)
    *(float4*)&wbuf[i*4] = *(const float4*)(wo + lane*24 + i*4);
  float a0 = 0.f, a1 = 0.f, a2 = 0.f;
  #pragma unroll
  for (int i = 0; i < 8; i++) {
    const float hv = b2f((unsigned short)hv8[i]);
    a0 = fmaf(hv, wbuf[i*3+0], a0);
    a1 = fmaf(hv, wbuf[i*3+1], a1);
    a2 = fmaf(hv, wbuf[i*3+2], a2);
  }
  #pragma unroll
  for (int o = 32; o; o >>= 1) {
    a0 += __shfl_xor(a0, o); a1 += __shfl_xor(a1, o); a2 += __shfl_xor(a2, o);
  }
  if (lane == 0) {
    const float* bo = (net ? tbo : sbo) + blk*3;
    sres[rloc][net][0] = a0 + bo[0];
    sres[rloc][net][1] = a1 + bo[1];
    sres[rloc][net][2] = a2 + bo[2];
  }
  __syncthreads();
  if (tid < 12) {
    const int rl = tid / 3, j = tid - 3*rl;
    const int r2 = blockIdx.x*4 + rl;
    const int q = r2 % 12;
    const int msk = (j + blk) & 1;
    const float s = sres[rl][0][j];
    const float t = sres[rl][1][j];
    const float uo = uinf[(size_t)r2*3 + j];
    const float unew = msk ? uo : (uo - t) * expf(-s);
    u[(size_t)r2*3 + j] = unew;
    const float prev = blk ? ld[(size_t)r2*3 + j] : 0.f;
    ld[(size_t)r2*3 + j] = prev - (msk ? 0.f : s);
    atomicAdd(&sraw[(blk*36 + q*3 + j)*2 + 0], unew);
    atomicAdd(&sraw[(blk*36 + q*3 + j)*2 + 1], unew * unew);
  }
}

__global__ void bn_finalize_kernel(const float* __restrict__ sraw, float* __restrict__ sab,
    float* __restrict__ ldadd, const float* __restrict__ lg, const float* __restrict__ bt, int blk)
{
  const int idx = threadIdx.x;
  if (idx < 36) {
    const int v = idx % 3;
    const float sum = sraw[(blk*36 + idx)*2 + 0];
    const float s2  = sraw[(blk*36 + idx)*2 + 1];
    const float bm  = sum * (1.f / 650.f);
    const float bvr = s2 * (1.f / 650.f) - bm * bm;
    const float g = lg[blk*3 + v];
    const float a = expf(g) * rsqrtf(bvr + 1e-5f);
    sab[(blk*36 + idx)*2 + 0] = a;
    sab[(blk*36 + idx)*2 + 1] = bt[blk*3 + v] - a * bm;
    ldadd[blk*36 + idx] = g - 0.5f * logf(bvr + 1e-5f);
  }
}

__global__ void loss_kernel(const float* __restrict__ u, const float* __restrict__ ld,
    const float* __restrict__ sab, const float* __restrict__ ldadd, float* __restrict__ out)
{
  const int bn = blockIdx.x * blockDim.x + threadIdx.x;
  if (bn >= BN_) return;
  float acc = 0.f;
  for (int t2 = 0; t2 < 12; t2++) {
    #pragma unroll
    for (int v = 0; v < 3; v++) {
      const int idx = t2*3 + v;
      const float a = sab[(5*36 + idx)*2 + 0];
      const float c = sab[(5*36 + idx)*2 + 1];
      const float ur = u[((size_t)bn*12 + t2)*3 + v];
      const float ub = fmaf(a, ur, c);
      acc += 0.5f*ub*ub + 0.5f*LOG2PI_ - ld[((size_t)bn*12 + t2)*3 + v];
    }
  }
  float lsum = 0.f;
  for (int i = 0; i < 6*36; i++) lsum += ldadd[i];
  out[bn] = acc - lsum;
}

// ============================================================
// workspace byte offsets (same map as round 2; kvb overlaps ab/hs/ht)
// ============================================================
#define O_WKV    (size_t)0
#define O_WSH    (size_t)3670016
#define O_WFF1   (size_t)4063232
#define O_WFF2   (size_t)6160384
#define O_WSIN   (size_t)8257536
#define O_WTIN   (size_t)11796480
#define O_WSHID  (size_t)15335424
#define O_WTHID  (size_t)27918336
#define O_EVB    (size_t)40501248
#define O_ATTB   (size_t)68456448
#define O_AVB    (size_t)74446848
#define O_AV2B   (size_t)82434048
#define O_HB     (size_t)90421248
#define O_FFSUM  (size_t)98408448
#define O_KVB    (size_t)106395648
#define O_AB     O_KVB
#define O_HS0    (O_KVB + 8985600)
#define O_HS1    (O_HS0 + 7987200)
#define O_HT0    (O_HS1 + 7987200)
#define O_HT1    (O_HT0 + 7987200)
#define O_UINF   (size_t)170293248
#define O_U      (size_t)170386848
#define O_LD     (size_t)170480448
#define O_SRAW   (size_t)170761248
#define O_SAB    (size_t)170762976
#define O_LDA    (size_t)170764704

static inline GZ mkgz(const void* A, const void* B, const float* bias, void* C,
                      const void* res, int act) {
  GZ g; g.A = (const unsigned short*)A; g.B = (const unsigned short*)B; g.bias = bias;
  g.C = (unsigned short*)C; g.res = (const unsigned short*)res; g.act = act; return g;
}

extern "C" void kernel_launch(void* const* d_in, const int* in_sizes, int n_in,
                              void* d_out, int out_size, void* d_ws, size_t ws_size,
                              hipStream_t stream)
{
  const float* enc   = (const float*)d_in[0];
  const float* tv    = (const float*)d_in[1];
  const float* Wsh   = (const float*)d_in[2];
  const float* bsh   = (const float*)d_in[3];
  const float* Wk    = (const float*)d_in[4];
  const float* bk    = (const float*)d_in[5];
  const float* Wv    = (const float*)d_in[6];
  const float* bv    = (const float*)d_in[7];
  const float* ln1s  = (const float*)d_in[8];
  const float* ln1b  = (const float*)d_in[9];
  const float* fw1   = (const float*)d_in[10];
  const float* fb1   = (const float*)d_in[11];
  const float* fw2   = (const float*)d_in[12];
  const float* fb2   = (const float*)d_in[13];
  const float* ln2s  = (const float*)d_in[14];
  const float* ln2b  = (const float*)d_in[15];
  const float* swin  = (const float*)d_in[16];
  const float* sbin  = (const float*)d_in[17];
  const float* swhid = (const float*)d_in[18];
  const float* sbhid = (const float*)d_in[19];
  const float* swout = (const float*)d_in[20];
  const float* sbout = (const float*)d_in[21];
  const float* twin  = (const float*)d_in[22];
  const float* tbin  = (const float*)d_in[23];
  const float* twhid = (const float*)d_in[24];
  const float* tbhid = (const float*)d_in[25];
  const float* twout = (const float*)d_in[26];
  const float* tbout = (const float*)d_in[27];
  const float* bnlg  = (const float*)d_in[28];
  const float* bnbt  = (const float*)d_in[29];

  char* ws = (char*)d_ws;
  unsigned short* wkv   = (unsigned short*)(ws + O_WKV);
  unsigned short* wsht  = (unsigned short*)(ws + O_WSH);
  unsigned short* wff1t = (unsigned short*)(ws + O_WFF1);
  unsigned short* wff2t = (unsigned short*)(ws + O_WFF2);
  unsigned short* wsint = (unsigned short*)(ws + O_WSIN);
  unsigned short* wtint = (unsigned short*)(ws + O_WTIN);
  unsigned short* wshid = (unsigned short*)(ws + O_WSHID);
  unsigned short* wthid = (unsigned short*)(ws + O_WTHID);
  unsigned short* evb   = (unsigned short*)(ws + O_EVB);
  unsigned short* attb  = (unsigned short*)(ws + O_ATTB);
  unsigned short* avb   = (unsigned short*)(ws + O_AVB);
  unsigned short* av2b  = (unsigned short*)(ws + O_AV2B);
  unsigned short* hb    = (unsigned short*)(ws + O_HB);
  unsigned short* ffsum = (unsigned short*)(ws + O_FFSUM);
  unsigned short* kvb   = (unsigned short*)(ws + O_KVB);
  unsigned short* ab    = (unsigned short*)(ws + O_AB);
  unsigned short* hs0   = (unsigned short*)(ws + O_HS0);
  unsigned short* hs1   = (unsigned short*)(ws + O_HS1);
  unsigned short* ht0   = (unsigned short*)(ws + O_HT0);
  unsigned short* ht1   = (unsigned short*)(ws + O_HT1);
  float* uinf  = (float*)(ws + O_UINF);
  float* u     = (float*)(ws + O_U);
  float* ld    = (float*)(ws + O_LD);
  float* sraw  = (float*)(ws + O_SRAW);
  float* sab   = (float*)(ws + O_SAB);
  float* lda   = (float*)(ws + O_LDA);
  float* out   = (float*)d_out;

  // ---- prep ----
  prep_evb<<<MKV_, 256, 0, stream>>>(enc, tv, evb);
  prep_attb<<<NROWS_, 256, 0, stream>>>(enc, attb);
  prep_wkv<<<dim3(1024, 4), 256, 0, stream>>>(Wk, Wv, wkv);
  prep_wsh<<<512, 256, 0, stream>>>(Wsh, wsht);
  prep_wff<<<dim3(512, 4, 2), 256, 0, stream>>>(fw1, fw2, wff1t, wff2t);
  prep_wnvp_in<<<dim3(512, 6, 2), 256, 0, stream>>>(swin, twin, wsint, wtint);
  prep_wnvp_hid<<<dim3(512, 24, 2), 256, 0, stream>>>(swhid, twhid, wshid, wthid);
  zero_stats_kernel<<<2, 256, 0, stream>>>(sraw);

  const GZ gnull = mkgz(nullptr, nullptr, nullptr, nullptr, nullptr, 0);

  // ---- shift GEMM: av0 = attb @ Wsh + bsh ----
  {
    GZ g = mkgz(attb, wsht, bsh, avb, nullptr, 0);
    gemm_bf16<128><<<dim3(4, 61, 1), 256, 0, stream>>>(g, gnull, NROWS_, 384,
        nullptr, nullptr, nullptr);
  }

  // ---- transformer layers ----
  for (int l = 0; l < 4; l++) {
    GZ g = mkgz(evb, wkv + (size_t)l*1024*448, nullptr, nullptr, nullptr, 0);
    gemm_bf16<128><<<dim3(8, 244, 1), 256, 0, stream>>>(g, gnull, MKV_, 448,
        kvb, bk + l*512, bv + l*512);
    attn_kernel<<<BN_, 512, 0, stream>>>(avb, kvb, ln1s + l*512, ln1b + l*512, av2b);
    GZ g1 = mkgz(av2b, wff1t + (size_t)l*512*512, fb1 + l*512, hb, nullptr, 1);
    gemm_bf16<128><<<dim3(4, 61, 1), 256, 0, stream>>>(g1, gnull, NROWS_, 512,
        nullptr, nullptr, nullptr);
    GZ g2 = mkgz(hb, wff2t + (size_t)l*512*512, fb2 + l*512, ffsum, av2b, 0);
    gemm_bf16<128><<<dim3(4, 61, 1), 256, 0, stream>>>(g2, gnull, NROWS_, 512,
        nullptr, nullptr, nullptr);
    if (l == 3)
      ln_kernel<<<1950, 256, 0, stream>>>(ffsum, ab, 576, ln2s + l*512, ln2b + l*512);
    else
      ln_kernel<<<1950, 256, 0, stream>>>(ffsum, avb, 512, ln2s + l*512, ln2b + l*512);
  }

  // ---- RealNVP ----
  pad_ab_kernel<<<NROWS_, 64, 0, stream>>>(ab);
  for (int blk = 0; blk < 6; blk++) {
    mu_kernel<<<31, 256, 0, stream>>>(tv, u, sab, uinf, ab, blk);
    {
      GZ gs = mkgz(ab, wsint + (size_t)blk*512*576, sbin + blk*512, hs0, nullptr, 2);
      GZ gt = mkgz(ab, wtint + (size_t)blk*512*576, tbin + blk*512, ht0, nullptr, 1);
      gemm_bf16<128><<<dim3(4, 61, 2), 256, 0, stream>>>(gs, gt, NROWS_, 576,
          nullptr, nullptr, nullptr);
    }
    for (int i = 0; i < 4; i++) {
      unsigned short* srcs = (i & 1) ? hs1 : hs0;
      unsigned short* dsts = (i & 1) ? hs0 : hs1;
      unsigned short* srct = (i & 1) ? ht1 : ht0;
      unsigned short* dstt = (i & 1) ? ht0 : ht1;
      GZ gs = mkgz(srcs, wshid + (size_t)(blk*4 + i)*512*512, sbhid + (blk*4 + i)*512, dsts, nullptr, 2);
      GZ gt = mkgz(srct, wthid + (size_t)(blk*4 + i)*512*512, tbhid + (blk*4 + i)*512, dstt, nullptr, 1);
      gemm_bf16<128><<<dim3(4, 61, 2), 256, 0, stream>>>(gs, gt, NROWS_, 512,
          nullptr, nullptr, nullptr);
    }
    out_couple_kernel<<<1950, 512, 0, stream>>>(hs0, ht0, swout, sbout, twout, tbout,
        uinf, u, ld, sraw, blk);
    bn_finalize_kernel<<<1, 64, 0, stream>>>(sraw, sab, lda, bnlg, bnbt, blk);
  }
  loss_kernel<<<3, 256, 0, stream>>>(u, ld, sab, lda, out);
}

// Round 5
// 2160.822 us; speedup vs baseline: 6.2169x; 1.2707x over previous
//
#include <hip/hip_runtime.h>
#include <math.h>

// ---- problem dims ----
#define BN_ 650
#define T_ 48
#define V_ 3
#define T2_ 12
#define NROWS_ 7800            // BN_*T2_
#define MKV_ 31200             // BN_*T_
#define LOG2PI_ 1.8378770664093453f

typedef short s8v __attribute__((ext_vector_type(8)));
typedef float f4v __attribute__((ext_vector_type(4)));

__device__ __forceinline__ float b2f(unsigned short h) {
  return __uint_as_float(((unsigned)h) << 16);
}
__device__ __forceinline__ unsigned short f2b(float f) {
  unsigned u = __float_as_uint(f);
  return (unsigned short)((u + 0x7fffu + ((u >> 16) & 1u)) >> 16);
}

// ============================================================
// Canonical bf16 MFMA GEMM: C[M,512] = act(A[M,Kp] @ BT[512,Kp]^T + bias)(+res)
// BT pre-transposed [N][Kp] bf16. Tile: BM x 128, 256 thr, 4 waves (2x2).
// Epilogue stages C tile in LDS, then coalesced 16B row-major writes.
// ============================================================
struct GZ {
  const unsigned short* A;
  const unsigned short* B;
  const float* bias;
  unsigned short* C;
  const unsigned short* res;
  int act;   // 0 none, 1 relu, 2 tanh
};

template<int BM>
__global__ __launch_bounds__(256)
void gemm_bf16(GZ g0, GZ g1, int M, int Kp)
{
  constexpr int MF = BM / 32;      // m-frags per wave
  constexpr int AU = BM / 32;      // A b128 units per thread
  __shared__ __align__(16) unsigned short As[2][BM * 72];
  __shared__ __align__(16) unsigned short Bs[2][128 * 72];
  GZ g = (blockIdx.z == 0) ? g0 : g1;
  const int tid = threadIdx.x;
  const int lane = tid & 63;
  const int wid = tid >> 6;
  const int wm = wid >> 1, wn = wid & 1;
  const int m0 = blockIdx.y * BM, n0 = blockIdx.x * 128;
  const int fr = lane & 15, fko = (lane >> 4) * 8;

  f4v acc[MF][4];
  #pragma unroll
  for (int i = 0; i < MF; i++)
    #pragma unroll
    for (int j = 0; j < 4; j++) acc[i][j] = (f4v){0.f, 0.f, 0.f, 0.f};

  const int steps = Kp >> 6;
  s8v ra[AU], rb[4];
  const s8v zed = (s8v){0,0,0,0,0,0,0,0};

  int arow[AU], akseg[AU], brow[4], bkseg[4];
  #pragma unroll
  for (int i = 0; i < AU; i++) { int gx = tid*AU + i; arow[i] = gx >> 3; akseg[i] = (gx & 7) * 8; }
  #pragma unroll
  for (int i = 0; i < 4; i++) { int gx = tid*4 + i; brow[i] = gx >> 3; bkseg[i] = (gx & 7) * 8; }

  // stage step 0
  #pragma unroll
  for (int i = 0; i < AU; i++)
    ra[i] = (m0 + arow[i] < M) ? *(const s8v*)(g.A + (size_t)(m0 + arow[i])*Kp + akseg[i]) : zed;
  #pragma unroll
  for (int i = 0; i < 4; i++)
    rb[i] = *(const s8v*)(g.B + (size_t)(n0 + brow[i])*Kp + bkseg[i]);
  #pragma unroll
  for (int i = 0; i < AU; i++) *(s8v*)&As[0][arow[i]*72 + akseg[i]] = ra[i];
  #pragma unroll
  for (int i = 0; i < 4; i++)  *(s8v*)&Bs[0][brow[i]*72 + bkseg[i]] = rb[i];
  __syncthreads();

  for (int s = 0; s < steps; s++) {
    if (s + 1 < steps) {
      const int ko = (s + 1) * 64;
      #pragma unroll
      for (int i = 0; i < AU; i++)
        ra[i] = (m0 + arow[i] < M) ? *(const s8v*)(g.A + (size_t)(m0 + arow[i])*Kp + ko + akseg[i]) : zed;
      #pragma unroll
      for (int i = 0; i < 4; i++)
        rb[i] = *(const s8v*)(g.B + (size_t)(n0 + brow[i])*Kp + ko + bkseg[i]);
    }
    const int buf = s & 1;
    #pragma unroll
    for (int kk = 0; kk < 2; kk++) {
      s8v af[MF], bfr[4];
      #pragma unroll
      for (int mm = 0; mm < MF; mm++)
        af[mm] = *(const s8v*)&As[buf][(wm*(BM/2) + mm*16 + fr)*72 + kk*32 + fko];
      #pragma unroll
      for (int nn = 0; nn < 4; nn++)
        bfr[nn] = *(const s8v*)&Bs[buf][(wn*64 + nn*16 + fr)*72 + kk*32 + fko];
      #pragma unroll
      for (int mm = 0; mm < MF; mm++)
        #pragma unroll
        for (int nn = 0; nn < 4; nn++)
          acc[mm][nn] = __builtin_amdgcn_mfma_f32_16x16x32_bf16(af[mm], bfr[nn], acc[mm][nn], 0, 0, 0);
    }
    if (s + 1 < steps) {
      #pragma unroll
      for (int i = 0; i < AU; i++) *(s8v*)&As[buf^1][arow[i]*72 + akseg[i]] = ra[i];
      #pragma unroll
      for (int i = 0; i < 4; i++)  *(s8v*)&Bs[buf^1][brow[i]*72 + bkseg[i]] = rb[i];
    }
    __syncthreads();
  }

  // ---- staged epilogue: acc -> LDS bf16 [BM][136] -> coalesced writes ----
  unsigned short* cs = &As[0][0];
  #pragma unroll
  for (int mm = 0; mm < MF; mm++) {
    #pragma unroll
    for (int nn = 0; nn < 4; nn++) {
      const int col = wn*64 + nn*16 + fr;
      const int gcol = n0 + col;
      const int row0 = wm*(BM/2) + mm*16 + (lane >> 4)*4;
      const float bc = g.bias ? g.bias[gcol] : 0.f;
      #pragma unroll
      for (int q = 0; q < 4; q++) {
        const int r = m0 + row0 + q;
        float v = acc[mm][nn][q] + bc;
        if (g.act == 1) v = fmaxf(v, 0.f);
        else if (g.act == 2) v = tanhf(v);
        if (g.res && r < M) v += b2f(g.res[(size_t)r*512 + gcol]);
        cs[(row0 + q)*136 + col] = f2b(v);
      }
    }
  }
  __syncthreads();
  for (int ch = tid; ch < BM*16; ch += 256) {
    const int row = ch >> 4, c8 = ch & 15;
    const int r = m0 + row;
    if (r < M)
      *(s8v*)(g.C + (size_t)r*512 + n0 + c8*8) = *(const s8v*)&cs[row*136 + c8*8];
  }
}

// ============================================================
// KV projection GEMM: C[31200,1024] = ev[31200,448] @ WT[1024,448]^T + bias
// A-tile resident in LDS (loaded once); loops over 8 n-slices streaming B.
// grid 244 x 512 thr (8 waves, 4x2). Row-major coalesced output.
// ============================================================
__global__ __launch_bounds__(512)
void gemm_kv(const unsigned short* __restrict__ A, const unsigned short* __restrict__ B,
             const float* __restrict__ kb, const float* __restrict__ vb,
             unsigned short* __restrict__ C, int M)
{
  __shared__ __align__(16) unsigned short Al[128*456];     // 116736 B
  __shared__ __align__(16) unsigned short Bst[2][128*72];  // 36864 B
  const int tid = threadIdx.x;
  const int lane = tid & 63, wid = tid >> 6;
  const int wm = wid >> 1, wn = wid & 1;                   // 4 x 2 waves
  const int m0 = blockIdx.x * 128;
  const int fr = lane & 15, fko = (lane >> 4) * 8;
  const s8v zed = (s8v){0,0,0,0,0,0,0,0};

  // ---- load A tile once: 128 rows x 448 cols ----
  #pragma unroll
  for (int i = 0; i < 14; i++) {
    const int idx = tid + i*512;
    const int row = idx / 56, c8 = idx - row*56;
    const s8v v = (m0 + row < M) ? *(const s8v*)(A + (size_t)(m0 + row)*448 + c8*8) : zed;
    *(s8v*)&Al[row*456 + c8*8] = v;
  }

  int brow[2], bkseg[2];
  #pragma unroll
  for (int i = 0; i < 2; i++) { const int gx = tid*2 + i; brow[i] = gx >> 3; bkseg[i] = (gx & 7)*8; }

  for (int ns = 0; ns < 8; ns++) {
    const unsigned short* Bn = B + (size_t)ns*128*448;
    s8v rb[2];
    #pragma unroll
    for (int i = 0; i < 2; i++)
      rb[i] = *(const s8v*)(Bn + (size_t)brow[i]*448 + bkseg[i]);
    #pragma unroll
    for (int i = 0; i < 2; i++) *(s8v*)&Bst[0][brow[i]*72 + bkseg[i]] = rb[i];
    __syncthreads();

    f4v acc[2][4];
    #pragma unroll
    for (int i = 0; i < 2; i++)
      #pragma unroll
      for (int j = 0; j < 4; j++) acc[i][j] = (f4v){0.f, 0.f, 0.f, 0.f};

    for (int s = 0; s < 7; s++) {
      if (s + 1 < 7) {
        const int ko = (s + 1)*64;
        #pragma unroll
        for (int i = 0; i < 2; i++)
          rb[i] = *(const s8v*)(Bn + (size_t)brow[i]*448 + ko + bkseg[i]);
      }
      const int buf = s & 1;
      #pragma unroll
      for (int kk = 0; kk < 2; kk++) {
        s8v af[2], bfr[4];
        #pragma unroll
        for (int mm = 0; mm < 2; mm++)
          af[mm] = *(const s8v*)&Al[(wm*32 + mm*16 + fr)*456 + s*64 + kk*32 + fko];
        #pragma unroll
        for (int nn = 0; nn < 4; nn++)
          bfr[nn] = *(const s8v*)&Bst[buf][(wn*64 + nn*16 + fr)*72 + kk*32 + fko];
        #pragma unroll
        for (int mm = 0; mm < 2; mm++)
          #pragma unroll
          for (int nn = 0; nn < 4; nn++)
            acc[mm][nn] = __builtin_amdgcn_mfma_f32_16x16x32_bf16(af[mm], bfr[nn], acc[mm][nn], 0, 0, 0);
      }
      if (s + 1 < 7) {
        #pragma unroll
        for (int i = 0; i < 2; i++) *(s8v*)&Bst[buf^1][brow[i]*72 + bkseg[i]] = rb[i];
      }
      __syncthreads();
    }

    // ---- staged epilogue for this n-slice ----
    unsigned short* cs = &Bst[0][0];   // [128][136] bf16 = 34816 B
    #pragma unroll
    for (int mm = 0; mm < 2; mm++) {
      #pragma unroll
      for (int nn = 0; nn < 4; nn++) {
        const int col = wn*64 + nn*16 + fr;
        const int cg = ns*128 + col;
        const int row0 = wm*32 + mm*16 + (lane >> 4)*4;
        const float bc = (cg < 512) ? kb[cg] : vb[cg - 512];
        #pragma unroll
        for (int q = 0; q < 4; q++)
          cs[(row0 + q)*136 + col] = f2b(acc[mm][nn][q] + bc);
      }
    }
    __syncthreads();
    #pragma unroll
    for (int i = 0; i < 4; i++) {
      const int ch = tid + i*512;
      const int row = ch >> 4, c8 = ch & 15;
      const int r = m0 + row;
      if (r < M)
        *(s8v*)(C + (size_t)r*1024 + ns*128 + c8*8) = *(const s8v*)&cs[row*136 + c8*8];
    }
    __syncthreads();
  }
}

// ============================================================
// Prep kernels
// ============================================================
__global__ void prep_evb(const float* __restrict__ enc, const float* __restrict__ tv,
                         unsigned short* __restrict__ evb)
{
  const int r = blockIdx.x;              // 0..31199
  const int bn = r / 48, t = r - bn * 48;
  for (int col = threadIdx.x; col < 448; col += 256) {
    unsigned short o = 0;
    if (col < 387) {
      const int v = col / 129, cc = col - v * 129;
      const float val = (cc < 128) ? enc[(((size_t)bn*3 + v)*48 + t)*128 + cc]
                                   : tv[((size_t)bn*3 + v)*48 + t];
      o = f2b(val);
    }
    evb[(size_t)r*448 + col] = o;
  }
}

__global__ void prep_attb(const float* __restrict__ enc, unsigned short* __restrict__ attb)
{
  const int r = blockIdx.x;              // 0..7799
  const int bn = r / 12, q = r - bn * 12;
  for (int col = threadIdx.x; col < 384; col += 256) {
    const int v = col >> 7, cc = col & 127;
    attb[(size_t)r*384 + col] = f2b(enc[(((size_t)bn*3 + v)*48 + 36 + q)*128 + cc]);
  }
}

__global__ void prep_wkv(const float* __restrict__ Wk, const float* __restrict__ Wv,
                         unsigned short* __restrict__ WT)
{
  const int l = blockIdx.y, n = blockIdx.x;            // n 0..1023
  const int kvs = n >> 9, h = (n >> 6) & 7, d = n & 63;
  const float* src = (kvs ? Wv : Wk) + ((size_t)(l*8 + h)*387)*64 + d;
  unsigned short* dst = WT + ((size_t)l*1024 + n)*448;
  for (int k = threadIdx.x; k < 448; k += 256)
    dst[k] = (k < 387) ? f2b(src[(size_t)k*64]) : 0;
}

__global__ void prep_wsh(const float* __restrict__ W, unsigned short* __restrict__ WT)
{
  const int n = blockIdx.x;                            // 0..511
  for (int k = threadIdx.x; k < 384; k += 256)
    WT[(size_t)n*384 + k] = f2b(W[(size_t)k*512 + n]);
}

__global__ void prep_wff(const float* __restrict__ W1, const float* __restrict__ W2,
                         unsigned short* __restrict__ T1, unsigned short* __restrict__ T2b)
{
  const int n = blockIdx.x, l = blockIdx.y, which = blockIdx.z;
  const float* src = (which ? W2 : W1) + (size_t)l*512*512;
  unsigned short* dst = (which ? T2b : T1) + ((size_t)l*512 + n)*512;
  for (int k = threadIdx.x; k < 512; k += 256)
    dst[k] = f2b(src[(size_t)k*512 + n]);
}

__global__ void prep_wnvp_in(const float* __restrict__ Ws, const float* __restrict__ Wt,
                             unsigned short* __restrict__ Ts, unsigned short* __restrict__ Tt)
{
  const int n = blockIdx.x, blk = blockIdx.y, net = blockIdx.z;
  const float* src = (net ? Wt : Ws) + (size_t)blk*515*512;
  unsigned short* dst = (net ? Tt : Ts) + ((size_t)blk*512 + n)*576;
  for (int k = threadIdx.x; k < 576; k += 256)
    dst[k] = (k < 515) ? f2b(src[(size_t)k*512 + n]) : 0;
}

__global__ void prep_wnvp_hid(const float* __restrict__ Ws, const float* __restrict__ Wt,
                              unsigned short* __restrict__ Ts, unsigned short* __restrict__ Tt)
{
  const int n = blockIdx.x, bi = blockIdx.y, net = blockIdx.z;   // bi = blk*4+i
  const float* src = (net ? Wt : Ws) + (size_t)bi*512*512;
  unsigned short* dst = (net ? Tt : Ts) + ((size_t)bi*512 + n)*512;
  for (int k = threadIdx.x; k < 512; k += 256)
    dst[k] = f2b(src[(size_t)k*512 + n]);
}

__global__ void pad_ab_kernel(unsigned short* __restrict__ ab)
{
  const int r = blockIdx.x;
  if (threadIdx.x < 64) ab[(size_t)r*576 + 512 + threadIdx.x] = 0;
}

__global__ void zero_stats_kernel(float* __restrict__ sraw)
{
  const int i = blockIdx.x * blockDim.x + threadIdx.x;
  if (i < 6*36*2) sraw[i] = 0.f;
}

// ============================================================
// Attention + LN1: 650 blocks x 512 thr; wave h owns head h.
// kvb row-major [31200][1024]: K cols 0..511, V cols 512..1023.
// K rows per lane (lane=key t); V via per-head LDS tile (lane=d col reads).
// ============================================================
__global__ __launch_bounds__(512)
void attn_kernel(const unsigned short* __restrict__ avb, const unsigned short* __restrict__ kvb,
                 const float* __restrict__ lns, const float* __restrict__ lnb,
                 unsigned short* __restrict__ av2b)
{
  const int b = blockIdx.x, tid = threadIdx.x;
  const int h = tid >> 6, lane = tid & 63;
  __shared__ float av [12][516];
  __shared__ float att[12][516];
  __shared__ unsigned short vsh[8][48][68];

  // cooperative load av rows to fp32 LDS
  for (int idx = tid; idx < 12*64; idx += 512) {
    const int v = idx >> 6, c8 = idx & 63;
    const s8v a8 = *(const s8v*)(avb + (((size_t)b*12 + v) << 9) + c8*8);
    #pragma unroll
    for (int j = 0; j < 8; j++) av[v][c8*8 + j] = b2f((unsigned short)a8[j]);
  }
  // per-wave: load V tile for head h (rows t, cols d)
  {
    const int t0 = lane >> 3, c8 = lane & 7;
    #pragma unroll
    for (int i = 0; i < 6; i++) {
      const int t = i*8 + t0;
      *(s8v*)&vsh[h][t][c8*8] =
          *(const s8v*)(kvb + (size_t)(b*48 + t)*1024 + 512 + h*64 + c8*8);
    }
  }
  __syncthreads();

  // K row (lane = key t, clamped), packed bf16, from row-major kvb
  const int tcl = (lane < 48) ? lane : 0;
  s8v kp[8];
  {
    const unsigned short* kr = kvb + (size_t)(b*48 + tcl)*1024 + h*64;
    #pragma unroll
    for (int i = 0; i < 8; i++) kp[i] = *(const s8v*)(kr + i*8);
  }

  // ---- scores: p[v] = Q[v] . K[lane] ----
  float p[12];
  #pragma unroll
  for (int v = 0; v < 12; v++) p[v] = 0.f;
  #pragma unroll
  for (int k8 = 0; k8 < 8; k8++) {
    float kf[8];
    #pragma unroll
    for (int j = 0; j < 8; j++) kf[j] = b2f((unsigned short)kp[k8][j]);
    #pragma unroll
    for (int v = 0; v < 12; v++) {
      const float* qp = &av[v][h*64 + k8*8];
      #pragma unroll
      for (int j = 0; j < 8; j++) p[v] = fmaf(qp[j], kf[j], p[v]);
    }
  }
  // ---- softmax over keys (lanes); key t valid iff t < 36+v ----
  #pragma unroll
  for (int v = 0; v < 12; v++) {
    const bool valid = (lane < 36 + v);
    float s = valid ? p[v]*0.125f : -1e30f;
    float m = s;
    #pragma unroll
    for (int off = 1; off < 64; off <<= 1) m = fmaxf(m, __shfl_xor(m, off));
    const float e = valid ? expf(s - m) : 0.f;
    float sum = e;
    #pragma unroll
    for (int off = 1; off < 64; off <<= 1) sum += __shfl_xor(sum, off);
    p[v] = e / sum;
  }
  // ---- PV: lane = d; o[v] = sum_t p[v][t] * V[t][d] (V col from LDS) ----
  float o[12];
  #pragma unroll
  for (int v = 0; v < 12; v++) o[v] = 0.f;
  #pragma unroll
  for (int t6 = 0; t6 < 6; t6++) {
    float vf[8];
    #pragma unroll
    for (int j = 0; j < 8; j++) vf[j] = b2f(vsh[h][t6*8 + j][lane]);
    #pragma unroll
    for (int j = 0; j < 8; j++) {
      const int tt = t6*8 + j;
      #pragma unroll
      for (int v = 0; v < 12; v++) o[v] = fmaf(__shfl(p[v], tt), vf[j], o[v]);
    }
  }
  #pragma unroll
  for (int v = 0; v < 12; v++) att[v][h*64 + lane] = o[v];
  __syncthreads();

  // ---- LN1: av2 = LN(av + att) ----
  for (int v = h; v < 12; v += 8) {
    float x[8], sm = 0.f, s2 = 0.f;
    #pragma unroll
    for (int j = 0; j < 8; j++) {
      const int c = lane*8 + j;
      const float t = av[v][c] + att[v][c];
      x[j] = t; sm += t; s2 += t*t;
    }
    #pragma unroll
    for (int off = 32; off; off >>= 1) { sm += __shfl_xor(sm, off); s2 += __shfl_xor(s2, off); }
    const float mean = sm * (1.f/512.f);
    const float var  = s2 * (1.f/512.f) - mean*mean;
    const float rr = rsqrtf(var + 1e-5f);
    #pragma unroll
    for (int j = 0; j < 8; j++) {
      const int c = lane*8 + j;
      av2b[(((size_t)b*12 + v) << 9) + c] = f2b((x[j] - mean)*rr*lns[c] + lnb[c]);
    }
  }
}

// LN over bf16 rows [7800][512] -> out with stride ldo
__global__ __launch_bounds__(256)
void ln_kernel(const unsigned short* __restrict__ in, unsigned short* __restrict__ out, int ldo,
               const float* __restrict__ s, const float* __restrict__ b)
{
  const int row = blockIdx.x*4 + (threadIdx.x >> 6);
  const int lane = threadIdx.x & 63;
  const s8v xv = *(const s8v*)(in + (size_t)row*512 + lane*8);
  float x[8], sm = 0.f, s2 = 0.f;
  #pragma unroll
  for (int j = 0; j < 8; j++) {
    const float t = b2f((unsigned short)xv[j]);
    x[j] = t; sm += t; s2 += t*t;
  }
  #pragma unroll
  for (int o = 32; o; o >>= 1) { sm += __shfl_xor(sm, o); s2 += __shfl_xor(s2, o); }
  const float mean = sm * (1.f/512.f);
  const float var  = s2 * (1.f/512.f) - mean*mean;
  const float rr = rsqrtf(var + 1e-5f);
  s8v o8;
  #pragma unroll
  for (int j = 0; j < 8; j++) {
    const int c = lane*8 + j;
    o8[j] = (short)f2b((x[j] - mean)*rr*s[c] + b[c]);
  }
  *(s8v*)(out + (size_t)row*ldo + lane*8) = o8;
}

// ============================================================
// NVP small kernels
// ============================================================
__global__ void mu_kernel(const float* __restrict__ tv, const float* __restrict__ u,
                          const float* __restrict__ sab, float* __restrict__ uinf,
                          unsigned short* __restrict__ ab, int blk)
{
  const int r = blockIdx.x*256 + threadIdx.x;
  if (r >= NROWS_) return;
  const int bn = r / 12, q = r - bn * 12;
  float uv[3];
  #pragma unroll
  for (int v = 0; v < 3; v++) {
    if (blk == 0) uv[v] = tv[((size_t)bn*3 + v)*48 + 36 + q];
    else {
      const float a = sab[((blk-1)*36 + q*3 + v)*2 + 0];
      const float c = sab[((blk-1)*36 + q*3 + v)*2 + 1];
      uv[v] = fmaf(a, u[(size_t)r*3 + v], c);
    }
  }
  #pragma unroll
  for (int v = 0; v < 3; v++) {
    uinf[(size_t)r*3 + v] = uv[v];
    ab[(size_t)r*576 + 512 + v] = f2b(((v + blk) & 1) ? uv[v] : 0.f);
  }
}

// out-layer (s and t nets) + coupling update + stats, fused.
__global__ __launch_bounds__(512)
void out_couple_kernel(const unsigned short* __restrict__ hs, const unsigned short* __restrict__ ht,
                const float* __restrict__ swo, const float* __restrict__ sbo,
                const float* __restrict__ two, const float* __restrict__ tbo,
                const float* __restrict__ uinf, float* __restrict__ u, float* __restrict__ ld,
                float* __restrict__ sraw, int blk)
{
  __shared__ float sres[4][2][3];
  const int tid = threadIdx.x;
  const int w = tid >> 6, lane = tid & 63;
  const int rloc = w >> 1, net = w & 1;
  const int r = blockIdx.x*4 + rloc;
  const unsigned short* hrow = (net ? ht : hs) + ((size_t)r << 9);
  const float* wo = (net ? two : swo) + (size_t)blk*512*3;

  const s8v hv8 = *(const s8v*)(hrow + lane*8);
  float wbuf[24];
  #pragma unroll
  for (int i = 0; i < 6; i++)
    *(float4*)&wbuf[i*4] = *(const float4*)(wo + lane*24 + i*4);
  float a0 = 0.f, a1 = 0.f, a2 = 0.f;
  #pragma unroll
  for (int i = 0; i < 8; i++) {
    const float hv = b2f((unsigned short)hv8[i]);
    a0 = fmaf(hv, wbuf[i*3+0], a0);
    a1 = fmaf(hv, wbuf[i*3+1], a1);
    a2 = fmaf(hv, wbuf[i*3+2], a2);
  }
  #pragma unroll
  for (int o = 32; o; o >>= 1) {
    a0 += __shfl_xor(a0, o); a1 += __shfl_xor(a1, o); a2 += __shfl_xor(a2, o);
  }
  if (lane == 0) {
    const float* bo = (net ? tbo : sbo) + blk*3;
    sres[rloc][net][0] = a0 + bo[0];
    sres[rloc][net][1] = a1 + bo[1];
    sres[rloc][net][2] = a2 + bo[2];
  }
  __syncthreads();
  if (tid < 12) {
    const int rl = tid / 3, j = tid - 3*rl;
    const int r2 = blockIdx.x*4 + rl;
    const int q = r2 % 12;
    const int msk = (j + blk) & 1;
    const float s = sres[rl][0][j];
    const float t = sres[rl][1][j];
    const float uo = uinf[(size_t)r2*3 + j];
    const float unew = msk ? uo : (uo - t) * expf(-s);
    u[(size_t)r2*3 + j] = unew;
    const float prev = blk ? ld[(size_t)r2*3 + j] : 0.f;
    ld[(size_t)r2*3 + j] = prev - (msk ? 0.f : s);
    atomicAdd(&sraw[(blk*36 + q*3 + j)*2 + 0], unew);
    atomicAdd(&sraw[(blk*36 + q*3 + j)*2 + 1], unew * unew);
  }
}

__global__ void bn_finalize_kernel(const float* __restrict__ sraw, float* __restrict__ sab,
    float* __restrict__ ldadd, const float* __restrict__ lg, const float* __restrict__ bt, int blk)
{
  const int idx = threadIdx.x;
  if (idx < 36) {
    const int v = idx % 3;
    const float sum = sraw[(blk*36 + idx)*2 + 0];
    const float s2  = sraw[(blk*36 + idx)*2 + 1];
    const float bm  = sum * (1.f / 650.f);
    const float bvr = s2 * (1.f / 650.f) - bm * bm;
    const float g = lg[blk*3 + v];
    const float a = expf(g) * rsqrtf(bvr + 1e-5f);
    sab[(blk*36 + idx)*2 + 0] = a;
    sab[(blk*36 + idx)*2 + 1] = bt[blk*3 + v] - a * bm;
    ldadd[blk*36 + idx] = g - 0.5f * logf(bvr + 1e-5f);
  }
}

__global__ void loss_kernel(const float* __restrict__ u, const float* __restrict__ ld,
    const float* __restrict__ sab, const float* __restrict__ ldadd, float* __restrict__ out)
{
  const int bn = blockIdx.x * blockDim.x + threadIdx.x;
  if (bn >= BN_) return;
  float acc = 0.f;
  for (int t2 = 0; t2 < 12; t2++) {
    #pragma unroll
    for (int v = 0; v < 3; v++) {
      const int idx = t2*3 + v;
      const float a = sab[(5*36 + idx)*2 + 0];
      const float c = sab[(5*36 + idx)*2 + 1];
      const float ur = u[((size_t)bn*12 + t2)*3 + v];
      const float ub = fmaf(a, ur, c);
      acc += 0.5f*ub*ub + 0.5f*LOG2PI_ - ld[((size_t)bn*12 + t2)*3 + v];
    }
  }
  float lsum = 0.f;
  for (int i = 0; i < 6*36; i++) lsum += ldadd[i];
  out[bn] = acc - lsum;
}

// ============================================================
// workspace byte offsets (kvb region reused by ab/hs/ht in NVP phase)
// ============================================================
#define O_WKV    (size_t)0
#define O_WSH    (size_t)3670016
#define O_WFF1   (size_t)4063232
#define O_WFF2   (size_t)6160384
#define O_WSIN   (size_t)8257536
#define O_WTIN   (size_t)11796480
#define O_WSHID  (size_t)15335424
#define O_WTHID  (size_t)27918336
#define O_EVB    (size_t)40501248
#define O_ATTB   (size_t)68456448
#define O_AVB    (size_t)74446848
#define O_AV2B   (size_t)82434048
#define O_HB     (size_t)90421248
#define O_FFSUM  (size_t)98408448
#define O_KVB    (size_t)106395648
#define O_AB     O_KVB
#define O_HS0    (O_KVB + 8985600)
#define O_HS1    (O_HS0 + 7987200)
#define O_HT0    (O_HS1 + 7987200)
#define O_HT1    (O_HT0 + 7987200)
#define O_UINF   (size_t)170293248
#define O_U      (size_t)170386848
#define O_LD     (size_t)170480448
#define O_SRAW   (size_t)170761248
#define O_SAB    (size_t)170762976
#define O_LDA    (size_t)170764704

static inline GZ mkgz(const void* A, const void* B, const float* bias, void* C,
                      const void* res, int act) {
  GZ g; g.A = (const unsigned short*)A; g.B = (const unsigned short*)B; g.bias = bias;
  g.C = (unsigned short*)C; g.res = (const unsigned short*)res; g.act = act; return g;
}

extern "C" void kernel_launch(void* const* d_in, const int* in_sizes, int n_in,
                              void* d_out, int out_size, void* d_ws, size_t ws_size,
                              hipStream_t stream)
{
  const float* enc   = (const float*)d_in[0];
  const float* tv    = (const float*)d_in[1];
  const float* Wsh   = (const float*)d_in[2];
  const float* bsh   = (const float*)d_in[3];
  const float* Wk    = (const float*)d_in[4];
  const float* bk    = (const float*)d_in[5];
  const float* Wv    = (const float*)d_in[6];
  const float* bv    = (const float*)d_in[7];
  const float* ln1s  = (const float*)d_in[8];
  const float* ln1b  = (const float*)d_in[9];
  const float* fw1   = (const float*)d_in[10];
  const float* fb1   = (const float*)d_in[11];
  const float* fw2   = (const float*)d_in[12];
  const float* fb2   = (const float*)d_in[13];
  const float* ln2s  = (const float*)d_in[14];
  const float* ln2b  = (const float*)d_in[15];
  const float* swin  = (const float*)d_in[16];
  const float* sbin  = (const float*)d_in[17];
  const float* swhid = (const float*)d_in[18];
  const float* sbhid = (const float*)d_in[19];
  const float* swout = (const float*)d_in[20];
  const float* sbout = (const float*)d_in[21];
  const float* twin  = (const float*)d_in[22];
  const float* tbin  = (const float*)d_in[23];
  const float* twhid = (const float*)d_in[24];
  const float* tbhid = (const float*)d_in[25];
  const float* twout = (const float*)d_in[26];
  const float* tbout = (const float*)d_in[27];
  const float* bnlg  = (const float*)d_in[28];
  const float* bnbt  = (const float*)d_in[29];

  char* ws = (char*)d_ws;
  unsigned short* wkv   = (unsigned short*)(ws + O_WKV);
  unsigned short* wsht  = (unsigned short*)(ws + O_WSH);
  unsigned short* wff1t = (unsigned short*)(ws + O_WFF1);
  unsigned short* wff2t = (unsigned short*)(ws + O_WFF2);
  unsigned short* wsint = (unsigned short*)(ws + O_WSIN);
  unsigned short* wtint = (unsigned short*)(ws + O_WTIN);
  unsigned short* wshid = (unsigned short*)(ws + O_WSHID);
  unsigned short* wthid = (unsigned short*)(ws + O_WTHID);
  unsigned short* evb   = (unsigned short*)(ws + O_EVB);
  unsigned short* attb  = (unsigned short*)(ws + O_ATTB);
  unsigned short* avb   = (unsigned short*)(ws + O_AVB);
  unsigned short* av2b  = (unsigned short*)(ws + O_AV2B);
  unsigned short* hb    = (unsigned short*)(ws + O_HB);
  unsigned short* ffsum = (unsigned short*)(ws + O_FFSUM);
  unsigned short* kvb   = (unsigned short*)(ws + O_KVB);
  unsigned short* ab    = (unsigned short*)(ws + O_AB);
  unsigned short* hs0   = (unsigned short*)(ws + O_HS0);
  unsigned short* hs1   = (unsigned short*)(ws + O_HS1);
  unsigned short* ht0   = (unsigned short*)(ws + O_HT0);
  unsigned short* ht1   = (unsigned short*)(ws + O_HT1);
  float* uinf  = (float*)(ws + O_UINF);
  float* u     = (float*)(ws + O_U);
  float* ld    = (float*)(ws + O_LD);
  float* sraw  = (float*)(ws + O_SRAW);
  float* sab   = (float*)(ws + O_SAB);
  float* lda   = (float*)(ws + O_LDA);
  float* out   = (float*)d_out;

  // ---- prep ----
  prep_evb<<<MKV_, 256, 0, stream>>>(enc, tv, evb);
  prep_attb<<<NROWS_, 256, 0, stream>>>(enc, attb);
  prep_wkv<<<dim3(1024, 4), 256, 0, stream>>>(Wk, Wv, wkv);
  prep_wsh<<<512, 256, 0, stream>>>(Wsh, wsht);
  prep_wff<<<dim3(512, 4, 2), 256, 0, stream>>>(fw1, fw2, wff1t, wff2t);
  prep_wnvp_in<<<dim3(512, 6, 2), 256, 0, stream>>>(swin, twin, wsint, wtint);
  prep_wnvp_hid<<<dim3(512, 24, 2), 256, 0, stream>>>(swhid, twhid, wshid, wthid);
  zero_stats_kernel<<<2, 256, 0, stream>>>(sraw);

  const GZ gnull = mkgz(nullptr, nullptr, nullptr, nullptr, nullptr, 0);

  // ---- shift GEMM: av0 = attb @ Wsh + bsh ----
  {
    GZ g = mkgz(attb, wsht, bsh, avb, nullptr, 0);
    gemm_bf16<128><<<dim3(4, 61, 1), 256, 0, stream>>>(g, gnull, NROWS_, 384);
  }

  // ---- transformer layers ----
  for (int l = 0; l < 4; l++) {
    gemm_kv<<<244, 512, 0, stream>>>(evb, wkv + (size_t)l*1024*448,
        bk + l*512, bv + l*512, kvb, MKV_);
    attn_kernel<<<BN_, 512, 0, stream>>>(avb, kvb, ln1s + l*512, ln1b + l*512, av2b);
    GZ g1 = mkgz(av2b, wff1t + (size_t)l*512*512, fb1 + l*512, hb, nullptr, 1);
    gemm_bf16<128><<<dim3(4, 61, 1), 256, 0, stream>>>(g1, gnull, NROWS_, 512);
    GZ g2 = mkgz(hb, wff2t + (size_t)l*512*512, fb2 + l*512, ffsum, av2b, 0);
    gemm_bf16<128><<<dim3(4, 61, 1), 256, 0, stream>>>(g2, gnull, NROWS_, 512);
    if (l == 3)
      ln_kernel<<<1950, 256, 0, stream>>>(ffsum, ab, 576, ln2s + l*512, ln2b + l*512);
    else
      ln_kernel<<<1950, 256, 0, stream>>>(ffsum, avb, 512, ln2s + l*512, ln2b + l*512);
  }

  // ---- RealNVP ----
  pad_ab_kernel<<<NROWS_, 64, 0, stream>>>(ab);
  for (int blk = 0; blk < 6; blk++) {
    mu_kernel<<<31, 256, 0, stream>>>(tv, u, sab, uinf, ab, blk);
    {
      GZ gs = mkgz(ab, wsint + (size_t)blk*512*576, sbin + blk*512, hs0, nullptr, 2);
      GZ gt = mkgz(ab, wtint + (size_t)blk*512*576, tbin + blk*512, ht0, nullptr, 1);
      gemm_bf16<128><<<dim3(4, 61, 2), 256, 0, stream>>>(gs, gt, NROWS_, 576);
    }
    for (int i = 0; i < 4; i++) {
      unsigned short* srcs = (i & 1) ? hs1 : hs0;
      unsigned short* dsts = (i & 1) ? hs0 : hs1;
      unsigned short* srct = (i & 1) ? ht1 : ht0;
      unsigned short* dstt = (i & 1) ? ht0 : ht1;
      GZ gs = mkgz(srcs, wshid + (size_t)(blk*4 + i)*512*512, sbhid + (blk*4 + i)*512, dsts, nullptr, 2);
      GZ gt = mkgz(srct, wthid + (size_t)(blk*4 + i)*512*512, tbhid + (blk*4 + i)*512, dstt, nullptr, 1);
      gemm_bf16<128><<<dim3(4, 61, 2), 256, 0, stream>>>(gs, gt, NROWS_, 512);
    }
    out_couple_kernel<<<1950, 512, 0, stream>>>(hs0, ht0, swout, sbout, twout, tbout,
        uinf, u, ld, sraw, blk);
    bn_finalize_kernel<<<1, 64, 0, stream>>>(sraw, sab, lda, bnlg, bnbt, blk);
  }
  loss_kernel<<<3, 256, 0, stream>>>(u, ld, sab, lda, out);
}